// Round 22
// baseline (2154.029 us; speedup 1.0000x reference)
//
#include <hip/hip_runtime.h>
#include <hip/hip_bf16.h>
#include <cfloat>
#include <cstdint>

// ---------------- constants ----------------
static constexpr int Bb   = 128;
static constexpr int SEQ  = 250;
static constexpr int DM   = 384;
static constexpr int NH   = 8;
static constexpr int DHd  = 48;
static constexpr int HID  = 342;
static constexpr int UU   = 30;   // U == u == 30

using bf16 = __hip_bfloat16;
typedef __attribute__((ext_vector_type(8))) short bf16x8;
typedef __attribute__((ext_vector_type(4))) float f32x4;

__device__ __forceinline__ float unpk_lo(uint32_t p){ return __builtin_bit_cast(float, p << 16); }
__device__ __forceinline__ float unpk_hi(uint32_t p){ return __builtin_bit_cast(float, p & 0xffff0000u); }

// LDS XOR swizzle for [row][64 bf16] tiles (128B rows), global_load_lds-compatible.
__device__ __forceinline__ int swz_st(int lane){ return (((lane & 7) ^ (lane >> 3)) << 3); }
__device__ __forceinline__ int swz_rd(int ks, int lane){ return ((((ks<<2) + (lane >> 4)) ^ (lane & 7)) << 3); }

// bijective XCD-aware block remap (m204 formula)
__device__ __forceinline__ int xcd_swz(int orig, int nwg){
  int q = nwg >> 3, r = nwg & 7;
  int x = orig & 7, i = orig >> 3;
  int start = (x < r) ? x*(q+1) : r*(q+1) + (x-r)*q;
  return start + i;
}

// ---------------- threefry2x32 (JAX-exact) ----------------
__device__ __forceinline__ uint32_t rotl32(uint32_t x, int n){ return (x<<n)|(x>>(32-n)); }
#define TF_R(x0,x1,r) { x0 += x1; x1 = rotl32(x1,(r)); x1 ^= x0; }
__device__ inline void threefry(uint32_t k0, uint32_t k1, uint32_t x0, uint32_t x1,
                                uint32_t &o0, uint32_t &o1){
  uint32_t ks2 = k0 ^ k1 ^ 0x1BD11BDAu;
  x0 += k0; x1 += k1;
  TF_R(x0,x1,13) TF_R(x0,x1,15) TF_R(x0,x1,26) TF_R(x0,x1,6)
  x0 += k1; x1 += ks2 + 1u;
  TF_R(x0,x1,17) TF_R(x0,x1,29) TF_R(x0,x1,16) TF_R(x0,x1,24)
  x0 += ks2; x1 += k0 + 2u;
  TF_R(x0,x1,13) TF_R(x0,x1,15) TF_R(x0,x1,26) TF_R(x0,x1,6)
  x0 += k0; x1 += k1 + 3u;
  TF_R(x0,x1,17) TF_R(x0,x1,29) TF_R(x0,x1,16) TF_R(x0,x1,24)
  x0 += k1; x1 += ks2 + 4u;
  TF_R(x0,x1,13) TF_R(x0,x1,15) TF_R(x0,x1,26) TF_R(x0,x1,6)
  x0 += ks2; x1 += k0 + 5u;
  o0 = x0; o1 = x1;
}

__global__ void idx_kernel(int* __restrict__ IDX){
  int i = blockIdx.x*256 + threadIdx.x;
  if (i >= 4*7500) return;
  int l = i / 7500;
  int t = i % 7500;
  uint32_t fk0, fk1;
  threefry(0u, 42u, 0u, (uint32_t)l, fk0, fk1);
  uint32_t a0,a1,b0,b1;
  threefry(fk0, fk1, 0u, 2u, a0, a1);
  threefry(fk0, fk1, 1u, 3u, b0, b1);
  uint32_t c0 = (t < 3750) ? (uint32_t)t          : (uint32_t)(t-3750);
  uint32_t c1 = (t < 3750) ? (uint32_t)(t+3750)   : (uint32_t)t;
  uint32_t y0, y1, hi, lo;
  threefry(a0, b0, c0, c1, y0, y1); hi = (t < 3750) ? y0 : y1;
  threefry(a1, b1, c0, c1, y0, y1); lo = (t < 3750) ? y0 : y1;
  uint32_t val = ((hi % 250u) * 46u + (lo % 250u)) % 250u;
  IDX[i] = (int)val;
}

// ---------------- block reductions (used by pool/final) ----------------
__device__ __forceinline__ float block_sum(float v, float* red){
  v += __shfl_down(v,32); v += __shfl_down(v,16); v += __shfl_down(v,8);
  v += __shfl_down(v,4);  v += __shfl_down(v,2);  v += __shfl_down(v,1);
  int lane = threadIdx.x & 63, wid = threadIdx.x >> 6, nw = blockDim.x >> 6;
  __syncthreads();
  if (lane == 0) red[wid] = v;
  __syncthreads();
  float r = red[0];
  for (int i=1;i<nw;i++) r += red[i];
  return r;
}

__device__ __forceinline__ float gelu_tanh(float x){
  float t = 0.7978845608028654f * (x + 0.044715f * x * x * x);
  return 0.5f * x * (1.f + tanhf(t));
}

// ---------------- pool (max over 4) + LN + pos ----------------
__global__ __launch_bounds__(384) void pool_ln_pos(const float* __restrict__ xin,
    const float* __restrict__ pos, const float* __restrict__ w, const float* __restrict__ b,
    float* __restrict__ X){
  __shared__ float red[8];
  int bs = blockIdx.x; int bb = bs / SEQ, s = bs % SEQ; int d = threadIdx.x;
  const float* xp = xin + ((size_t)bb*1000 + (size_t)s*4)*DM + d;
  float v = fmaxf(fmaxf(xp[0], xp[DM]), fmaxf(xp[2*DM], xp[3*DM]));
  float mu = block_sum(v, red) * (1.f/DM);
  float diff = v - mu;
  float var = block_sum(diff*diff, red) * (1.f/DM);
  X[(size_t)bs*DM + d] = diff * rsqrtf(var + 1e-5f) * w[d] + b[d] + pos[(size_t)s*DM + d];
}

// ---------------- wave-per-row LayerNorm ----------------
template<int MODE>
__global__ __launch_bounds__(256) void ln_wave(const float* __restrict__ in,
    float* __restrict__ o32, bf16* __restrict__ o16, bf16* __restrict__ olo,
    const float* __restrict__ w, const float* __restrict__ b){
  size_t row = (size_t)blockIdx.x*4 + (threadIdx.x >> 6);
  int lane = threadIdx.x & 63;
  const float* rp = in + row*DM;
  float v[6];
  #pragma unroll
  for (int i = 0; i < 6; i++) v[i] = rp[lane + 64*i];
  float s = v[0]+v[1]+v[2]+v[3]+v[4]+v[5];
  #pragma unroll
  for (int off = 32; off; off >>= 1) s += __shfl_xor(s, off);
  float mu = s * (1.f/DM);
  float q = 0.f;
  #pragma unroll
  for (int i = 0; i < 6; i++){ float d = v[i]-mu; q += d*d; }
  #pragma unroll
  for (int off = 32; off; off >>= 1) q += __shfl_xor(q, off);
  float rs = rsqrtf(q*(1.f/DM) + 1e-5f);
  #pragma unroll
  for (int i = 0; i < 6; i++){
    int d = lane + 64*i;
    float y = (v[i]-mu)*rs*w[d] + b[d];
    if (MODE == 0) o32[row*DM + d] = y;
    if (MODE == 1) o16[row*DM + d] = __float2bfloat16(y);
    if (MODE == 2){
      bf16 h = __float2bfloat16(y);
      o16[row*DM + d] = h;
      olo[row*DM + d] = __float2bfloat16(y - __bfloat162float(h));
    }
  }
}

// ---------------- bf16 MFMA GEMM ----------------
__device__ __forceinline__ void gload16(const void* g, void* l){
  __builtin_amdgcn_global_load_lds(
      (__attribute__((address_space(1))) void*)(g),
      (__attribute__((address_space(3))) void*)(l), 16, 0, 0);
}

// Dense GEMM: C[M x 384] = A @ W ; EPI: 0=f32 store 1=f32 += 2=bf16 gelu 3=bf16 store
template<int EPI>
__global__ __launch_bounds__(256) void mfma_gemm(
    const bf16* __restrict__ A, const bf16* __restrict__ WT,
    const float* __restrict__ bias, float* __restrict__ Cf, bf16* __restrict__ Cb,
    const bf16* __restrict__ zpage)
{
  __shared__ bf16 As[128*64];
  __shared__ bf16 Bs[128*64];
  const int tid = threadIdx.x;
  const int wid = tid >> 6, lane = tid & 63;
  const int wr = wid >> 1, wc = wid & 1;
  const int wg = xcd_swz(blockIdx.x, 750);
  const int bm = (wg / 3) * 128;
  const int bn = (wg % 3) * 128;
  const int srow = lane >> 3;
  const int scolz = swz_st(lane);

  f32x4 acc[4][4] = {};
  for (int ck = 0; ck < 6; ck++){
    const int kk0 = ck * 64;
    __syncthreads();
    #pragma unroll
    for (int s = 0; s < 4; s++){
      int row = wid*32 + s*8 + srow;
      gload16(A + (size_t)(bm + row)*DM + kk0 + scolz, &As[(wid*32 + s*8)*64]);
    }
    #pragma unroll
    for (int s = 0; s < 4; s++){
      int row = wid*32 + s*8 + srow;
      gload16(WT + (size_t)(bn + row)*DM + kk0 + scolz, &Bs[(wid*32 + s*8)*64]);
    }
    __syncthreads();
    #pragma unroll
    for (int ks = 0; ks < 2; ks++){
      const int fo = swz_rd(ks, lane);
      bf16x8 af[4], bg[4];
      #pragma unroll
      for (int m = 0; m < 4; m++)
        af[m] = *(const bf16x8*)&As[(wr*64 + m*16 + (lane & 15))*64 + fo];
      #pragma unroll
      for (int n = 0; n < 4; n++)
        bg[n] = *(const bf16x8*)&Bs[(wc*64 + n*16 + (lane & 15))*64 + fo];
      #pragma unroll
      for (int m = 0; m < 4; m++)
        #pragma unroll
        for (int n = 0; n < 4; n++)
          acc[m][n] = __builtin_amdgcn_mfma_f32_16x16x32_bf16(af[m], bg[n], acc[m][n], 0, 0, 0);
    }
  }
  const int c_l = lane & 15, r4 = (lane >> 4) * 4;
  #pragma unroll
  for (int m = 0; m < 4; m++){
    #pragma unroll
    for (int n = 0; n < 4; n++){
      #pragma unroll
      for (int r = 0; r < 4; r++){
        int token = bm + wr*64 + m*16 + r4 + r;
        int col   = bn + wc*64 + n*16 + c_l;
        float v = acc[m][n][r] + bias[col];
        if (EPI == 0)      Cf[(size_t)token*DM + col] = v;
        else if (EPI == 1) Cf[(size_t)token*DM + col] += v;
        else if (EPI == 2) Cb[(size_t)token*DM + col] = __float2bfloat16(gelu_tanh(v));
        else               Cb[(size_t)token*DM + col] = __float2bfloat16(v);
      }
    }
  }
}

// group-aware conv1 GEMM
template<int EPI, int KIN>
__global__ __launch_bounds__(256) void mfma_c1g(
    const bf16* __restrict__ A, const bf16* __restrict__ WG,
    const float* __restrict__ bias, float* __restrict__ Cf, bf16* __restrict__ Cb,
    const bf16* __restrict__ zpage)
{
  __shared__ bf16 As[128*64];
  __shared__ bf16 Bs[128*64];
  const int tid = threadIdx.x;
  const int wid = tid >> 6, lane = tid & 63;
  const int wr = wid >> 1, wc = wid & 1;
  const int wg = xcd_swz(blockIdx.x, 750);
  const int bm = (wg / 3) * 128;
  const int g  = wg % 3;
  const int srow = lane >> 3;
  const int scolz = swz_st(lane);

  f32x4 acc[4][4] = {};
  for (int ck = 0; ck < 6; ck++){
    const int tap = ck >> 1;
    const int kk0 = (ck & 1) * 64;
    __syncthreads();
    #pragma unroll
    for (int s = 0; s < 4; s++){
      int row = wid*32 + s*8 + srow;
      int token = bm + row;
      int l = token - (token/SEQ)*SEQ;
      int ls = l + tap - 1;
      bool valid = (ls >= 0) && (ls < SEQ);
      const bf16* src = valid ? (A + (size_t)(token + tap - 1)*DM + g*KIN + kk0 + scolz) : zpage;
      gload16(src, &As[(wid*32 + s*8)*64]);
    }
    #pragma unroll
    for (int s = 0; s < 4; s++){
      int row = wid*32 + s*8 + srow;
      gload16(WG + ((size_t)(g*3 + tap)*128 + row)*128 + kk0 + scolz, &Bs[(wid*32 + s*8)*64]);
    }
    __syncthreads();
    #pragma unroll
    for (int ks = 0; ks < 2; ks++){
      const int fo = swz_rd(ks, lane);
      bf16x8 af[4], bg[4];
      #pragma unroll
      for (int m = 0; m < 4; m++)
        af[m] = *(const bf16x8*)&As[(wr*64 + m*16 + (lane & 15))*64 + fo];
      #pragma unroll
      for (int n = 0; n < 4; n++)
        bg[n] = *(const bf16x8*)&Bs[(wc*64 + n*16 + (lane & 15))*64 + fo];
      #pragma unroll
      for (int m = 0; m < 4; m++)
        #pragma unroll
        for (int n = 0; n < 4; n++)
          acc[m][n] = __builtin_amdgcn_mfma_f32_16x16x32_bf16(af[m], bg[n], acc[m][n], 0, 0, 0);
    }
  }
  const int c_l = lane & 15, r4 = (lane >> 4) * 4;
  #pragma unroll
  for (int m = 0; m < 4; m++){
    #pragma unroll
    for (int n = 0; n < 4; n++){
      #pragma unroll
      for (int r = 0; r < 4; r++){
        int token = bm + wr*64 + m*16 + r4 + r;
        int cl    = wc*64 + n*16 + c_l;
        if (EPI == 2){
          if (cl < 114){
            int col = g*114 + cl;
            float v = acc[m][n][r] + bias[col];
            Cb[(size_t)token*DM + col] = __float2bfloat16(gelu_tanh(v));
          }
        } else {
          int col = g*128 + cl;
          float v = acc[m][n][r] + bias[col];
          Cf[(size_t)token*DM + col] += v;
        }
      }
    }
  }
}

// fused Q+K split-bf16 f32-accurate GEMM; 128x64 tile (2x2 waves, 64x32 per wave)
__global__ __launch_bounds__(256) void mfma_qk2(
    const bf16* __restrict__ Ahi, const bf16* __restrict__ Alo,
    const bf16* __restrict__ WqT, const bf16* __restrict__ WkT,
    const float* __restrict__ bq, const float* __restrict__ bk,
    bf16* __restrict__ Qhi, bf16* __restrict__ Qlo,
    bf16* __restrict__ Khi, bf16* __restrict__ Klo)
{
  __shared__ bf16 As[128*64];
  __shared__ bf16 BsQ[64*64];
  __shared__ bf16 BsK[64*64];
  const int tid = threadIdx.x;
  const int wid = tid >> 6, lane = tid & 63;
  const int wr = wid >> 1, wc = wid & 1;
  const int wg = xcd_swz(blockIdx.x, 1500);
  const int bm = (wg / 6) * 128;
  const int bn = (wg % 6) * 64;
  const int srow = lane >> 3;
  const int scolz = swz_st(lane);

  f32x4 accQ[4][2] = {};
  f32x4 accK[4][2] = {};
  for (int kk6 = 0; kk6 < 6; kk6++){
    const int kk0 = kk6 * 64;
    for (int p = 0; p < 3; p++){
      const size_t wo = (p == 1) ? (size_t)DM*DM : 0;
      __syncthreads();
      if (p != 1){
        const bf16* Asrc = (p == 0) ? Ahi : Alo;
        #pragma unroll
        for (int s = 0; s < 4; s++){
          int row = wid*32 + s*8 + srow;
          gload16(Asrc + (size_t)(bm + row)*DM + kk0 + scolz, &As[(wid*32 + s*8)*64]);
        }
      }
      #pragma unroll
      for (int s = 0; s < 2; s++){
        int row = wid*16 + s*8 + srow;
        gload16(WqT + wo + (size_t)(bn + row)*DM + kk0 + scolz, &BsQ[(wid*16 + s*8)*64]);
        gload16(WkT + wo + (size_t)(bn + row)*DM + kk0 + scolz, &BsK[(wid*16 + s*8)*64]);
      }
      __syncthreads();
      #pragma unroll
      for (int ks = 0; ks < 2; ks++){
        const int fo = swz_rd(ks, lane);
        bf16x8 af[4], bgq[2], bgk[2];
        #pragma unroll
        for (int m = 0; m < 4; m++)
          af[m] = *(const bf16x8*)&As[(wr*64 + m*16 + (lane & 15))*64 + fo];
        #pragma unroll
        for (int n = 0; n < 2; n++){
          bgq[n] = *(const bf16x8*)&BsQ[(wc*32 + n*16 + (lane & 15))*64 + fo];
          bgk[n] = *(const bf16x8*)&BsK[(wc*32 + n*16 + (lane & 15))*64 + fo];
        }
        #pragma unroll
        for (int m = 0; m < 4; m++)
          #pragma unroll
          for (int n = 0; n < 2; n++){
            accQ[m][n] = __builtin_amdgcn_mfma_f32_16x16x32_bf16(af[m], bgq[n], accQ[m][n], 0, 0, 0);
            accK[m][n] = __builtin_amdgcn_mfma_f32_16x16x32_bf16(af[m], bgk[n], accK[m][n], 0, 0, 0);
          }
      }
    }
  }
  const int c_l = lane & 15, r4 = (lane >> 4) * 4;
  #pragma unroll
  for (int m = 0; m < 4; m++)
    #pragma unroll
    for (int n = 0; n < 2; n++)
      #pragma unroll
      for (int r = 0; r < 4; r++){
        int token = bm + wr*64 + m*16 + r4 + r;
        int col   = bn + wc*32 + n*16 + c_l;
        size_t off = (size_t)token*DM + col;
        float qv = accQ[m][n][r] + bq[col];
        float kv = accK[m][n][r] + bk[col];
        bf16 qh = __float2bfloat16(qv);
        bf16 kh = __float2bfloat16(kv);
        Qhi[off] = qh; Qlo[off] = __float2bfloat16(qv - __bfloat162float(qh));
        Khi[off] = kh; Klo[off] = __float2bfloat16(kv - __bfloat162float(kh));
      }
}

// ---------------- conv2 as MFMA ----------------
__global__ __launch_bounds__(256) void conv2_mfma(
    const bf16* __restrict__ HT, const bf16* __restrict__ W2T,
    const float* __restrict__ bias, float* __restrict__ X,
    const bf16* __restrict__ zpage)
{
  __shared__ bf16 As[128*64];
  __shared__ bf16 Bs[128*64];
  const int tid = threadIdx.x;
  const int wid = tid >> 6, lane = tid & 63;
  const int wr = wid >> 1, wc = wid & 1;
  const int wg = xcd_swz(blockIdx.x, 768);
  const int bn = (wg % 3) * 128;
  const int g  = (wg / 3) & 1;
  const int b  = wg / 6;
  const int srow = lane >> 3;
  const int scolz = swz_st(lane);
  const bf16* Wbase = W2T + (size_t)g*3*128*128;

  f32x4 acc[4][4] = {};
  for (int ck = 0; ck < 6; ck++){
    const int tap = ck >> 1;
    const int kk0 = (ck & 1) * 64;
    __syncthreads();
    #pragma unroll
    for (int s = 0; s < 4; s++){
      gload16(Wbase + ((size_t)tap*128 + wid*32 + s*8 + srow)*128 + kk0 + scolz, &As[(wid*32 + s*8)*64]);
    }
    #pragma unroll
    for (int s = 0; s < 4; s++){
      int row = wid*32 + s*8 + srow;
      int sd = bn + row + tap - 1;
      const bf16* src = (sd >= 0 && sd < DM)
        ? (HT + (((size_t)b*DM + sd)*2 + g)*128 + kk0 + scolz) : zpage;
      gload16(src, &Bs[(wid*32 + s*8)*64]);
    }
    __syncthreads();
    #pragma unroll
    for (int ks = 0; ks < 2; ks++){
      const int fo = swz_rd(ks, lane);
      bf16x8 af[4], bg[4];
      #pragma unroll
      for (int m = 0; m < 4; m++)
        af[m] = *(const bf16x8*)&As[(wr*64 + m*16 + (lane & 15))*64 + fo];
      #pragma unroll
      for (int n = 0; n < 4; n++)
        bg[n] = *(const bf16x8*)&Bs[(wc*64 + n*16 + (lane & 15))*64 + fo];
      #pragma unroll
      for (int m = 0; m < 4; m++)
        #pragma unroll
        for (int n = 0; n < 4; n++)
          acc[m][n] = __builtin_amdgcn_mfma_f32_16x16x32_bf16(af[m], bg[n], acc[m][n], 0, 0, 0);
    }
  }
  const int c_l = lane & 15, r4 = (lane >> 4) * 4;
  #pragma unroll
  for (int m = 0; m < 4; m++){
    #pragma unroll
    for (int n = 0; n < 4; n++){
      #pragma unroll
      for (int r = 0; r < 4; r++){
        int lo = wr*64 + m*16 + r4 + r;
        if (lo < 125){
          int d = bn + wc*64 + n*16 + c_l;
          float v = acc[m][n][r] + bias[g*125 + lo];
          X[((size_t)b*SEQ + g*125 + lo)*DM + d] += gelu_tanh(v);
        }
      }
    }
  }
}

// ---------------- transpose H[b][l][d] bf16 -> HT[b][d][g*128+li] bf16 ----------------
__global__ __launch_bounds__(256) void transpose_ht(const bf16* __restrict__ H,
                                                    bf16* __restrict__ HT){
  __shared__ bf16 t[68][66];
  int d0 = blockIdx.x * 64;
  int p0 = blockIdx.y * 64;
  int b  = blockIdx.z;
  int tid = threadIdx.x;
  int l0 = p0 - 3;
  for (int i = tid; i < 68*64; i += 256){
    int r = i >> 6, c = i & 63;
    int l = l0 + r;
    bf16 v = __float2bfloat16(0.f);
    if (l >= 0 && l < SEQ) v = H[((size_t)b*SEQ + l)*DM + d0 + c];
    t[r][c] = v;
  }
  __syncthreads();
  for (int i = tid; i < 64*64; i += 256){
    int rr = i >> 6, cc = i & 63;
    int p = p0 + cc;
    int gg = p >> 7, li = p & 127;
    int l = gg*125 + li;
    bf16 v = __float2bfloat16(0.f);
    if (li < 125 && l < SEQ) v = t[l - l0][rr];
    HT[((size_t)b*DM + d0 + rr)*256 + p] = v;
  }
}

// ---------------- weight prep ----------------
__global__ void zfill(bf16* z){ z[threadIdx.x] = __float2bfloat16(0.f); }

__global__ __launch_bounds__(256) void build_projT(const float* __restrict__ Wv,
    const float* __restrict__ Wo, bf16* __restrict__ WvT, bf16* __restrict__ WoT){
  __shared__ float t[32][33];
  int mat = blockIdx.z;
  const float* W = (mat < 4) ? (Wv + (size_t)mat*DM*DM) : (Wo + (size_t)(mat-4)*DM*DM);
  bf16* WT = (mat < 4) ? (WvT + (size_t)mat*DM*DM) : (WoT + (size_t)(mat-4)*DM*DM);
  int k0 = blockIdx.y*32, n0 = blockIdx.x*32;
  int tx = threadIdx.x & 31, ty = threadIdx.x >> 5;
  #pragma unroll
  for (int r = 0; r < 32; r += 8)
    t[ty + r][tx] = W[(size_t)(k0 + ty + r)*DM + n0 + tx];
  __syncthreads();
  #pragma unroll
  for (int r = 0; r < 32; r += 8)
    WT[(size_t)(n0 + ty + r)*DM + k0 + tx] = __float2bfloat16(t[tx][ty + r]);
}

__global__ __launch_bounds__(256) void build_qkhl(const float* __restrict__ Wq,
    const float* __restrict__ Wk, bf16* __restrict__ WT){
  __shared__ float t[32][33];
  int mat = blockIdx.z;
  const float* W = (mat < 4) ? (Wq + (size_t)mat*DM*DM) : (Wk + (size_t)(mat-4)*DM*DM);
  bf16* hi = WT + (size_t)mat*2*DM*DM;
  bf16* lo = hi + (size_t)DM*DM;
  int k0 = blockIdx.y*32, n0 = blockIdx.x*32;
  int tx = threadIdx.x & 31, ty = threadIdx.x >> 5;
  #pragma unroll
  for (int r = 0; r < 32; r += 8)
    t[ty + r][tx] = W[(size_t)(k0 + ty + r)*DM + n0 + tx];
  __syncthreads();
  #pragma unroll
  for (int r = 0; r < 32; r += 8){
    float w = t[tx][ty + r];
    bf16 h = __float2bfloat16(w);
    hi[(size_t)(n0 + ty + r)*DM + k0 + tx] = h;
    lo[(size_t)(n0 + ty + r)*DM + k0 + tx] = __float2bfloat16(w - __bfloat162float(h));
  }
}

__global__ void build_biasA(const float* __restrict__ bin, float* __restrict__ bias_pad){
  int i = blockIdx.x*256 + threadIdx.x;
  if (i >= 4*DM) return;
  int l = i/DM, n = i%DM;
  bias_pad[i] = (n < HID) ? bin[l*HID + n] : 0.f;
}

__global__ void build_c1aG(const float* __restrict__ W, bf16* __restrict__ WG){
  int i = blockIdx.x*256 + threadIdx.x;
  if (i >= 4*3*3*128*128) return;
  int k   = i & 127;
  int n   = (i >> 7) & 127;
  int tap = (i / 16384) % 3;
  int g   = (i / 49152) % 3;
  int l   = i / 147456;
  float v = 0.f;
  if (n < 114)
    v = W[(((size_t)l*HID + g*114 + n)*128 + k)*3 + tap];
  WG[i] = __float2bfloat16(v);
}

__global__ void build_c1bG(const float* __restrict__ W, bf16* __restrict__ WG){
  int i = blockIdx.x*256 + threadIdx.x;
  if (i >= 4*3*3*128*128) return;
  int k   = i & 127;
  int n   = (i >> 7) & 127;
  int tap = (i / 16384) % 3;
  int g   = (i / 49152) % 3;
  int l   = i / 147456;
  float v = 0.f;
  if (k < 114)
    v = W[(((size_t)l*DM + g*128 + n)*114 + k)*3 + tap];
  WG[i] = __float2bfloat16(v);
}

__global__ void build_c2T(const float* __restrict__ W, bf16* __restrict__ WT){
  int i = blockIdx.x*256 + threadIdx.x;
  if (i >= 4*2*3*128*128) return;
  int li = i & 127;
  int lo = (i >> 7) & 127;
  int t  = (i / 16384) % 3;
  int g  = (i / 49152) % 2;
  int l  = i / 98304;
  float v = 0.f;
  if (lo < 125 && li < 125)
    v = W[(((size_t)l*SEQ + g*125 + lo)*125 + li)*3 + t];
  WT[i] = __float2bfloat16(v);
}

// ---------------- fused probe + top-k + attention context per (b,h) ----------------
// Q fragments loaded DIRECTLY into registers (A-layout: row = m*16+(lane&15),
// k = (lane>>4)*8) — no LDS staging, no per-tile staging barrier.
static constexpr int SSTR = 260;   // f32 stride
static constexpr int VSTR = 132;   // u32 stride
__global__ __launch_bounds__(256) void attn_fused(
    const bf16* __restrict__ Qhi, const bf16* __restrict__ Qlo,
    const bf16* __restrict__ Khi, const bf16* __restrict__ Klo,
    const bf16* __restrict__ V16, const int* __restrict__ idx,
    bf16* __restrict__ CTX, const bf16* __restrict__ zpage)
{
  __shared__ float Ssh[32*SSTR];
  __shared__ uint32_t Vsh[DHd*VSTR];
  __shared__ int   IDXsh[32*UU];
  __shared__ float Msh[256];
  __shared__ int   TOPsh[32];
  __shared__ float invsh[32];
  __shared__ float vpart[5][DHd];
  __shared__ float vmean[DHd];
  __shared__ int   mark[SEQ];
  const int bh = xcd_swz(blockIdx.x, Bb*NH);
  const int h = bh & 7; const int b = bh >> 3;
  const int tid = threadIdx.x;
  const int wid = tid >> 6, lane = tid & 63;
  const size_t base = (size_t)(b*SEQ)*DM + h*DHd;
  const int c_l = lane & 15, r4 = (lane >> 4) * 4;
  const int kb  = (lane >> 4) * 8;

  // K fragments into VGPRs (once)
  bf16x8 kfh[4][2] = {};
  bf16x8 kfl[4][2] = {};
  {
    const int colb = wid*64 + c_l;
    #pragma unroll
    for (int n = 0; n < 4; n++){
      int col = colb + n*16;
      int cc  = (col < SEQ) ? col : (SEQ-1);
      const bf16* ph = Khi + base + (size_t)cc*DM;
      const bf16* pl = Klo + base + (size_t)cc*DM;
      kfh[n][0] = *(const bf16x8*)(ph + kb);
      kfl[n][0] = *(const bf16x8*)(pl + kb);
      if (kb + 32 < DHd){
        kfh[n][1] = *(const bf16x8*)(ph + kb + 32);
        kfl[n][1] = *(const bf16x8*)(pl + kb + 32);
      }
    }
  }
  // stage V early (latency hides under probe phase) + mark init
  const uint16_t* vp16 = (const uint16_t*)(V16 + base);
  for (int i = tid; i < DHd*128; i += 256){
    int dh = i >> 7, jp = i & 127;
    uint32_t v = 0;
    if (jp < 125){
      uint32_t a = vp16[(size_t)(2*jp)*DM + dh];
      uint32_t c = vp16[(size_t)(2*jp+1)*DM + dh];
      v = a | (c << 16);
    }
    Vsh[dh*VSTR + jp] = v;
  }
  for (int i = tid; i < SEQ; i += 256) mark[i] = -1;

  // ---- phase 1: probe over 8 Q-tiles ----
  for (int t = 0; t < 8; t++){
    const int r0 = t*32;
    // Q fragments direct to registers
    bf16x8 qfh[2][2], qfl[2][2];
    #pragma unroll
    for (int m = 0; m < 2; m++){
      qfh[m][0] = bf16x8{}; qfh[m][1] = bf16x8{};
      qfl[m][0] = bf16x8{}; qfl[m][1] = bf16x8{};
      int row = r0 + m*16 + c_l;
      if (row < SEQ){
        const bf16* ph = Qhi + base + (size_t)row*DM;
        const bf16* pl = Qlo + base + (size_t)row*DM;
        qfh[m][0] = *(const bf16x8*)(ph + kb);
        qfl[m][0] = *(const bf16x8*)(pl + kb);
        if (kb + 32 < DHd){
          qfh[m][1] = *(const bf16x8*)(ph + kb + 32);
          qfl[m][1] = *(const bf16x8*)(pl + kb + 32);
        }
      }
    }
    for (int i = tid; i < 32*UU; i += 256){
      int r = i / UU;
      int row = r0 + r;
      IDXsh[i] = (row < SEQ) ? idx[row*UU + (i - r*UU)] : 0;
    }
    f32x4 acc[2][4] = {};
    __builtin_amdgcn_s_setprio(1);
    #pragma unroll
    for (int p = 0; p < 3; p++){
      #pragma unroll
      for (int ks = 0; ks < 2; ks++){
        #pragma unroll
        for (int m = 0; m < 2; m++){
          bf16x8 af = (p < 2) ? qfh[m][ks] : qfl[m][ks];
          #pragma unroll
          for (int n = 0; n < 4; n++){
            bf16x8 bg = (p == 1) ? kfl[n][ks] : kfh[n][ks];
            acc[m][n] = __builtin_amdgcn_mfma_f32_16x16x32_bf16(af, bg, acc[m][n], 0, 0, 0);
          }
        }
      }
    }
    __builtin_amdgcn_s_setprio(0);
    #pragma unroll
    for (int m = 0; m < 2; m++)
      #pragma unroll
      for (int n = 0; n < 4; n++)
        #pragma unroll
        for (int r = 0; r < 4; r++)
          Ssh[(m*16 + r4 + r)*SSTR + wid*64 + n*16 + c_l] = acc[m][n][r];
    __syncthreads();
    {
      int rl = tid >> 3, s8 = tid & 7;
      int row = r0 + rl;
      float mx = -FLT_MAX, sm = 0.f;
      #pragma unroll
      for (int uu = 0; uu < 4; uu++){
        int u = s8 + uu*8;
        if (u < UU){
          int c = IDXsh[rl*UU + u];
          float v = Ssh[rl*SSTR + c];
          mx = fmaxf(mx, v); sm += v;
        }
      }
      #pragma unroll
      for (int off = 4; off; off >>= 1){
        mx = fmaxf(mx, __shfl_xor(mx, off));
        sm += __shfl_xor(sm, off);
      }
      if (s8 == 0 && row < SEQ) Msh[row] = mx - sm*(1.f/UU);
    }
    __syncthreads();
  }
  // ---- top-k (JAX tie-break) into TOPsh — single-wave, barrier-free ----
  if (wid == 0){
    float vals[4]; int ids[4];
    #pragma unroll
    for (int r = 0; r < 4; r++){
      int l = r*64 + lane;
      if (l < SEQ){ vals[r] = Msh[l]; ids[r] = l; }
      else        { vals[r] = -FLT_MAX; ids[r] = 1<<30; }
    }
    for (int sel = 0; sel < UU; sel++){
      float bv = -FLT_MAX; int bi = 1<<30;
      #pragma unroll
      for (int r = 0; r < 4; r++)
        if (vals[r] > bv || (vals[r] == bv && ids[r] < bi)){ bv = vals[r]; bi = ids[r]; }
      #pragma unroll
      for (int off = 32; off; off >>= 1){
        float ov = __shfl_xor(bv, off);
        int   oi = __shfl_xor(bi, off);
        if (ov > bv || (ov == bv && oi < bi)){ bv = ov; bi = oi; }
      }
      if (lane == 0) TOPsh[sel] = bi;
      #pragma unroll
      for (int r = 0; r < 4; r++) if (ids[r] == bi) vals[r] = -FLT_MAX;
    }
  }
  __syncthreads();
  if (tid < UU) mark[TOPsh[tid]] = tid;

  // ---- phase 2: ctx for top-30 rows ----
  {
    // Q fragments for top rows direct to registers
    bf16x8 qfh[2][2], qfl[2][2];
    #pragma unroll
    for (int m = 0; m < 2; m++){
      qfh[m][0] = bf16x8{}; qfh[m][1] = bf16x8{};
      qfl[m][0] = bf16x8{}; qfl[m][1] = bf16x8{};
      int u = m*16 + c_l;
      if (u < UU){
        int tr = TOPsh[u];
        const bf16* ph = Qhi + base + (size_t)tr*DM;
        const bf16* pl = Qlo + base + (size_t)tr*DM;
        qfh[m][0] = *(const bf16x8*)(ph + kb);
        qfl[m][0] = *(const bf16x8*)(pl + kb);
        if (kb + 32 < DHd){
          qfh[m][1] = *(const bf16x8*)(ph + kb + 32);
          qfl[m][1] = *(const bf16x8*)(pl + kb + 32);
        }
      }
    }
    f32x4 acc[2][4] = {};
    __builtin_amdgcn_s_setprio(1);
    #pragma unroll
    for (int p = 0; p < 3; p++){
      #pragma unroll
      for (int ks = 0; ks < 2; ks++){
        #pragma unroll
        for (int m = 0; m < 2; m++){
          bf16x8 af = (p < 2) ? qfh[m][ks] : qfl[m][ks];
          #pragma unroll
          for (int n = 0; n < 4; n++){
            bf16x8 bg = (p == 1) ? kfl[n][ks] : kfh[n][ks];
            acc[m][n] = __builtin_amdgcn_mfma_f32_16x16x32_bf16(af, bg, acc[m][n], 0, 0, 0);
          }
        }
      }
    }
    __builtin_amdgcn_s_setprio(0);
    #pragma unroll
    for (int m = 0; m < 2; m++)
      #pragma unroll
      for (int n = 0; n < 4; n++)
        #pragma unroll
        for (int r = 0; r < 4; r++)
          Ssh[(m*16 + r4 + r)*SSTR + wid*64 + n*16 + c_l] = acc[m][n][r];
  }
  __syncthreads();
  {
    const float scale = 0.14433756729740643f;
    for (int rr = 0; rr < 8; rr++){
      int row = wid*8 + rr;
      float* Sr = &Ssh[row*SSTR];
      if (row < UU){
        float xs[4];
        #pragma unroll
        for (int j = 0; j < 4; j++){
          int c = lane + 64*j;
          xs[j] = (c < SEQ) ? Sr[c]*scale : -FLT_MAX;
        }
        float mx = fmaxf(fmaxf(xs[0],xs[1]), fmaxf(xs[2],xs[3]));
        #pragma unroll
        for (int off = 32; off; off >>= 1) mx = fmaxf(mx, __shfl_xor(mx, off));
        float sm = 0.f;
        #pragma unroll
        for (int j = 0; j < 4; j++){
          int c = lane + 64*j;
          float e = (c < SEQ) ? expf(xs[j]-mx) : 0.f;
          Sr[c] = e;
          sm += e;
        }
        #pragma unroll
        for (int off = 32; off; off >>= 1) sm += __shfl_xor(sm, off);
        if (lane == 0) invsh[row] = 1.f/sm;
      } else {
        #pragma unroll
        for (int j = 0; j < 4; j++) Sr[lane + 64*j] = 0.f;
      }
    }
    if (tid < 240){
      int dh = tid % DHd, pr = tid / DHd;
      const uint32_t* vr = &Vsh[dh*VSTR + pr*25];
      float s = 0.f;
      #pragma unroll
      for (int z = 0; z < 25; z++){ uint32_t vp = vr[z]; s += unpk_lo(vp) + unpk_hi(vp); }
      vpart[pr][dh] = s;
    }
  }
  __syncthreads();
  if (tid < DHd)
    vmean[tid] = (vpart[0][tid]+vpart[1][tid]+vpart[2][tid]+vpart[3][tid]+vpart[4][tid]) * (1.f/SEQ);

  if (wid < 3){
    const int dh0 = wid*16;
    f32x4 acc2[2] = {};
    __builtin_amdgcn_s_setprio(1);
    for (int kc = 0; kc < 8; kc++){
      bf16x8 bv = *(const bf16x8*)&Vsh[(dh0 + (lane & 15))*VSTR + kc*16 + (lane >> 4)*4];
      #pragma unroll
      for (int m = 0; m < 2; m++){
        const float* pr = &Ssh[(m*16 + (lane & 15))*SSTR + kc*32 + (lane >> 4)*8];
        bf16x8 pa;
        #pragma unroll
        for (int i = 0; i < 8; i++){
          bf16 hh = __float2bfloat16(pr[i]);
          pa[i] = *reinterpret_cast<short*>(&hh);
        }
        acc2[m] = __builtin_amdgcn_mfma_f32_16x16x32_bf16(pa, bv, acc2[m], 0, 0, 0);
      }
    }
    __builtin_amdgcn_s_setprio(0);
    #pragma unroll
    for (int m = 0; m < 2; m++)
      #pragma unroll
      for (int r = 0; r < 4; r++){
        int u = m*16 + r4 + r;
        if (u < UU){
          float val = acc2[m][r] * invsh[u];
          CTX[(size_t)(b*SEQ + TOPsh[u])*DM + h*DHd + dh0 + c_l] = __float2bfloat16(val);
        }
      }
  }
  __syncthreads();
  for (int i = tid; i < SEQ*DHd; i += 256){
    int l = i / DHd, dh = i - l*DHd;
    if (mark[l] < 0)
      CTX[(size_t)(b*SEQ + l)*DM + h*DHd + dh] = __float2bfloat16(vmean[dh]);
  }
}

// ---------------- final: max over L -> LN(ln2) -> FC ----------------
__global__ __launch_bounds__(384) void final_kernel(const float* __restrict__ Hin,
    const float* __restrict__ w, const float* __restrict__ bparm,
    const float* __restrict__ fcw, const float* __restrict__ fcb, float* __restrict__ out){
  __shared__ float red[8];
  __shared__ float ybuf[DM];
  int b = blockIdx.x; int d = threadIdx.x;
  const float* hp = Hin + (size_t)b*SEQ*DM + d;
  float mx = -FLT_MAX;
  for (int l=0;l<SEQ;l++) mx = fmaxf(mx, hp[(size_t)l*DM]);
  float mu = block_sum(mx, red) * (1.f/DM);
  float diff = mx - mu;
  float var = block_sum(diff*diff, red) * (1.f/DM);
  float y = diff * rsqrtf(var + 1e-5f) * w[d] + bparm[d];
  ybuf[d] = y;
  __syncthreads();
  if (d < 10){
    float acc = fcb[d];
    for (int k=0;k<DM;k++) acc += ybuf[k] * fcw[k*10 + d];
    out[b*10 + d] = acc;
  }
}

// ---------------- host orchestration ----------------
extern "C" void kernel_launch(void* const* d_in, const int* in_sizes, int n_in,
                              void* d_out, int out_size, void* d_ws, size_t ws_size,
                              hipStream_t stream) {
  const float* x     = (const float*)d_in[0];
  const float* pos   = (const float*)d_in[1];
  const float* lniw  = (const float*)d_in[2];
  const float* lnib  = (const float*)d_in[3];
  const float* lnAw  = (const float*)d_in[4];
  const float* lnAb  = (const float*)d_in[5];
  const float* Wq    = (const float*)d_in[6];
  const float* bq    = (const float*)d_in[7];
  const float* Wk    = (const float*)d_in[8];
  const float* bk    = (const float*)d_in[9];
  const float* Wv    = (const float*)d_in[10];
  const float* bv    = (const float*)d_in[11];
  const float* Wo    = (const float*)d_in[12];
  const float* bo    = (const float*)d_in[13];
  const float* lnBw  = (const float*)d_in[14];
  const float* lnBb  = (const float*)d_in[15];
  const float* c1aw  = (const float*)d_in[16];
  const float* c1ab  = (const float*)d_in[17];
  const float* c1bw  = (const float*)d_in[18];
  const float* c1bb  = (const float*)d_in[19];
  const float* lnCw  = (const float*)d_in[20];
  const float* lnCb  = (const float*)d_in[21];
  const float* c2w   = (const float*)d_in[22];
  const float* c2b   = (const float*)d_in[23];
  const float* ln2w  = (const float*)d_in[24];
  const float* ln2b  = (const float*)d_in[25];
  const float* fcw   = (const float*)d_in[26];
  const float* fcb   = (const float*)d_in[27];
  float* out = (float*)d_out;

  const size_t ACT  = (size_t)Bb*SEQ*DM;        // 12,288,000
  float* Xb  = (float*)d_ws;
  float* Hb  = Xb  + ACT;
  float* Qb  = Hb  + ACT;
  float* Kb  = Qb  + ACT;
  float* Vb  = Kb  + ACT;
  float* biasA = Vb + ACT;
  int*   TOP = (int*)(biasA + 4*DM);            // unused (layout stability)
  int*   IDX = TOP + (size_t)Bb*NH*UU;
  bf16*  Hb16 = (bf16*)(IDX + 4*7500);
  bf16*  G1   = Hb16 + ACT;
  bf16*  WvT  = G1   + ACT;
  bf16*  WoT  = WvT  + (size_t)4*DM*DM;
  bf16*  WaG  = WoT  + (size_t)4*DM*DM;
  bf16*  WbG  = WaG  + (size_t)12*DM*DM;
  bf16*  WqkT = WbG  + (size_t)12*DM*DM;
  bf16*  W2T  = WqkT + (size_t)16*DM*DM;
  bf16*  zp   = W2T  + (size_t)4*2*3*128*128;

  bf16* Qhi = (bf16*)Qb; bf16* Qlo = Qhi + ACT;
  bf16* Khi = (bf16*)Kb; bf16* Klo = Khi + ACT;
  bf16* V16 = (bf16*)Vb;

  zfill<<<dim3(1), dim3(256), 0, stream>>>(zp);
  hipMemsetAsync(G1, 0, ACT*sizeof(bf16), stream);
  idx_kernel<<<dim3(118), dim3(256), 0, stream>>>(IDX);
  build_projT<<<dim3(12,12,8), dim3(256), 0, stream>>>(Wv, Wo, WvT, WoT);
  build_qkhl<<<dim3(12,12,8), dim3(256), 0, stream>>>(Wq, Wk, WqkT);
  build_biasA<<<dim3(6), dim3(256), 0, stream>>>(c1ab, biasA);
  build_c1aG<<<dim3(2304), dim3(256), 0, stream>>>(c1aw, WaG);
  build_c1bG<<<dim3(2304), dim3(256), 0, stream>>>(c1bw, WbG);
  build_c2T<<<dim3(1536), dim3(256), 0, stream>>>(c2w, W2T);
  pool_ln_pos<<<dim3(32000), dim3(384), 0, stream>>>(x, pos, lniw, lnib, Xb);

  for (int l = 0; l < 4; l++){
    const size_t wofs = (size_t)l*DM*DM;
    bf16* Alo16 = (bf16*)Hb;
    bf16* CTX16 = Hb16;
    bf16* HTb   = (bf16*)Qb;
    ln_wave<2><<<dim3(8000), dim3(256), 0, stream>>>(Xb, (float*)nullptr, Hb16, Alo16, lnAw + l*DM, lnAb + l*DM);
    mfma_qk2<<<dim3(1500), dim3(256), 0, stream>>>(Hb16, Alo16,
        WqkT + (size_t)l*2*DM*DM, WqkT + (size_t)(4+l)*2*DM*DM,
        bq + l*DM, bk + l*DM, Qhi, Qlo, Khi, Klo);
    mfma_gemm<3><<<dim3(750), dim3(256), 0, stream>>>(Hb16, WvT + wofs, bv + l*DM, (float*)nullptr, V16, zp);
    attn_fused<<<dim3(Bb*NH), dim3(256), 0, stream>>>(Qhi, Qlo, Khi, Klo, V16, IDX + l*7500, CTX16, zp);
    mfma_gemm<1><<<dim3(750), dim3(256), 0, stream>>>(CTX16, WoT + wofs, bo + l*DM, Xb, (bf16*)nullptr, zp);

    ln_wave<1><<<dim3(8000), dim3(256), 0, stream>>>(Xb, (float*)nullptr, Hb16, (bf16*)nullptr, lnBw + l*DM, lnBb + l*DM);
    mfma_c1g<2,128><<<dim3(750), dim3(256), 0, stream>>>(Hb16, WaG + (size_t)l*3*3*128*128, biasA + l*DM, (float*)nullptr, G1, zp);
    mfma_c1g<1,114><<<dim3(750), dim3(256), 0, stream>>>(G1, WbG + (size_t)l*3*3*128*128, c1bb + l*DM, Xb, (bf16*)nullptr, zp);

    ln_wave<1><<<dim3(8000), dim3(256), 0, stream>>>(Xb, (float*)nullptr, Hb16, (bf16*)nullptr, lnCw + l*DM, lnCb + l*DM);
    transpose_ht<<<dim3(6,4,Bb), dim3(256), 0, stream>>>(Hb16, HTb);
    conv2_mfma<<<dim3(768), dim3(256), 0, stream>>>(HTb, W2T + (size_t)l*2*3*128*128, c2b + l*SEQ, Xb, zp);
  }

  ln_wave<0><<<dim3(8000), dim3(256), 0, stream>>>(Xb, Hb, (bf16*)nullptr, (bf16*)nullptr, ln2w, ln2b);
  final_kernel<<<dim3(Bb), dim3(384), 0, stream>>>(Hb, ln2w, ln2b, fcw, fcb, out);
}

// Round 23
// 1990.284 us; speedup vs baseline: 1.0823x; 1.0823x over previous
//
#include <hip/hip_runtime.h>
#include <hip/hip_bf16.h>
#include <cfloat>
#include <cstdint>

// ---------------- constants ----------------
static constexpr int Bb   = 128;
static constexpr int SEQ  = 250;
static constexpr int DM   = 384;
static constexpr int NH   = 8;
static constexpr int DHd  = 48;
static constexpr int HID  = 342;
static constexpr int UU   = 30;   // U == u == 30

using bf16 = __hip_bfloat16;
typedef __attribute__((ext_vector_type(8))) short bf16x8;
typedef __attribute__((ext_vector_type(4))) float f32x4;

__device__ __forceinline__ float unpk_lo(uint32_t p){ return __builtin_bit_cast(float, p << 16); }
__device__ __forceinline__ float unpk_hi(uint32_t p){ return __builtin_bit_cast(float, p & 0xffff0000u); }

// LDS XOR swizzle for [row][64 bf16] tiles (128B rows), global_load_lds-compatible.
__device__ __forceinline__ int swz_st(int lane){ return (((lane & 7) ^ (lane >> 3)) << 3); }
__device__ __forceinline__ int swz_rd(int ks, int lane){ return ((((ks<<2) + (lane >> 4)) ^ (lane & 7)) << 3); }

// bijective XCD-aware block remap (m204 formula)
__device__ __forceinline__ int xcd_swz(int orig, int nwg){
  int q = nwg >> 3, r = nwg & 7;
  int x = orig & 7, i = orig >> 3;
  int start = (x < r) ? x*(q+1) : r*(q+1) + (x-r)*q;
  return start + i;
}

// ---------------- threefry2x32 (JAX-exact) ----------------
__device__ __forceinline__ uint32_t rotl32(uint32_t x, int n){ return (x<<n)|(x>>(32-n)); }
#define TF_R(x0,x1,r) { x0 += x1; x1 = rotl32(x1,(r)); x1 ^= x0; }
__device__ inline void threefry(uint32_t k0, uint32_t k1, uint32_t x0, uint32_t x1,
                                uint32_t &o0, uint32_t &o1){
  uint32_t ks2 = k0 ^ k1 ^ 0x1BD11BDAu;
  x0 += k0; x1 += k1;
  TF_R(x0,x1,13) TF_R(x0,x1,15) TF_R(x0,x1,26) TF_R(x0,x1,6)
  x0 += k1; x1 += ks2 + 1u;
  TF_R(x0,x1,17) TF_R(x0,x1,29) TF_R(x0,x1,16) TF_R(x0,x1,24)
  x0 += ks2; x1 += k0 + 2u;
  TF_R(x0,x1,13) TF_R(x0,x1,15) TF_R(x0,x1,26) TF_R(x0,x1,6)
  x0 += k0; x1 += k1 + 3u;
  TF_R(x0,x1,17) TF_R(x0,x1,29) TF_R(x0,x1,16) TF_R(x0,x1,24)
  x0 += k1; x1 += ks2 + 4u;
  TF_R(x0,x1,13) TF_R(x0,x1,15) TF_R(x0,x1,26) TF_R(x0,x1,6)
  x0 += ks2; x1 += k0 + 5u;
  o0 = x0; o1 = x1;
}

__global__ void idx_kernel(int* __restrict__ IDX){
  int i = blockIdx.x*256 + threadIdx.x;
  if (i >= 4*7500) return;
  int l = i / 7500;
  int t = i % 7500;
  uint32_t fk0, fk1;
  threefry(0u, 42u, 0u, (uint32_t)l, fk0, fk1);
  uint32_t a0,a1,b0,b1;
  threefry(fk0, fk1, 0u, 2u, a0, a1);
  threefry(fk0, fk1, 1u, 3u, b0, b1);
  uint32_t c0 = (t < 3750) ? (uint32_t)t          : (uint32_t)(t-3750);
  uint32_t c1 = (t < 3750) ? (uint32_t)(t+3750)   : (uint32_t)t;
  uint32_t y0, y1, hi, lo;
  threefry(a0, b0, c0, c1, y0, y1); hi = (t < 3750) ? y0 : y1;
  threefry(a1, b1, c0, c1, y0, y1); lo = (t < 3750) ? y0 : y1;
  uint32_t val = ((hi % 250u) * 46u + (lo % 250u)) % 250u;
  IDX[i] = (int)val;
}

// ---------------- block reductions (used by pool/final) ----------------
__device__ __forceinline__ float block_sum(float v, float* red){
  v += __shfl_down(v,32); v += __shfl_down(v,16); v += __shfl_down(v,8);
  v += __shfl_down(v,4);  v += __shfl_down(v,2);  v += __shfl_down(v,1);
  int lane = threadIdx.x & 63, wid = threadIdx.x >> 6, nw = blockDim.x >> 6;
  __syncthreads();
  if (lane == 0) red[wid] = v;
  __syncthreads();
  float r = red[0];
  for (int i=1;i<nw;i++) r += red[i];
  return r;
}

__device__ __forceinline__ float gelu_tanh(float x){
  float t = 0.7978845608028654f * (x + 0.044715f * x * x * x);
  return 0.5f * x * (1.f + tanhf(t));
}

// ---------------- pool (max over 4) + LN + pos ----------------
__global__ __launch_bounds__(384) void pool_ln_pos(const float* __restrict__ xin,
    const float* __restrict__ pos, const float* __restrict__ w, const float* __restrict__ b,
    float* __restrict__ X){
  __shared__ float red[8];
  int bs = blockIdx.x; int bb = bs / SEQ, s = bs % SEQ; int d = threadIdx.x;
  const float* xp = xin + ((size_t)bb*1000 + (size_t)s*4)*DM + d;
  float v = fmaxf(fmaxf(xp[0], xp[DM]), fmaxf(xp[2*DM], xp[3*DM]));
  float mu = block_sum(v, red) * (1.f/DM);
  float diff = v - mu;
  float var = block_sum(diff*diff, red) * (1.f/DM);
  X[(size_t)bs*DM + d] = diff * rsqrtf(var + 1e-5f) * w[d] + b[d] + pos[(size_t)s*DM + d];
}

// ---------------- wave-per-row LayerNorm ----------------
template<int MODE>
__global__ __launch_bounds__(256) void ln_wave(const float* __restrict__ in,
    float* __restrict__ o32, bf16* __restrict__ o16, bf16* __restrict__ olo,
    const float* __restrict__ w, const float* __restrict__ b){
  size_t row = (size_t)blockIdx.x*4 + (threadIdx.x >> 6);
  int lane = threadIdx.x & 63;
  const float* rp = in + row*DM;
  float v[6];
  #pragma unroll
  for (int i = 0; i < 6; i++) v[i] = rp[lane + 64*i];
  float s = v[0]+v[1]+v[2]+v[3]+v[4]+v[5];
  #pragma unroll
  for (int off = 32; off; off >>= 1) s += __shfl_xor(s, off);
  float mu = s * (1.f/DM);
  float q = 0.f;
  #pragma unroll
  for (int i = 0; i < 6; i++){ float d = v[i]-mu; q += d*d; }
  #pragma unroll
  for (int off = 32; off; off >>= 1) q += __shfl_xor(q, off);
  float rs = rsqrtf(q*(1.f/DM) + 1e-5f);
  #pragma unroll
  for (int i = 0; i < 6; i++){
    int d = lane + 64*i;
    float y = (v[i]-mu)*rs*w[d] + b[d];
    if (MODE == 0) o32[row*DM + d] = y;
    if (MODE == 1) o16[row*DM + d] = __float2bfloat16(y);
    if (MODE == 2){
      bf16 h = __float2bfloat16(y);
      o16[row*DM + d] = h;
      olo[row*DM + d] = __float2bfloat16(y - __bfloat162float(h));
    }
  }
}

// ---------------- bf16 MFMA GEMM ----------------
__device__ __forceinline__ void gload16(const void* g, void* l){
  __builtin_amdgcn_global_load_lds(
      (__attribute__((address_space(1))) void*)(g),
      (__attribute__((address_space(3))) void*)(l), 16, 0, 0);
}

// Dense GEMM: C[M x 384] = A @ W ; EPI: 0=f32 store 1=f32 += 2=bf16 gelu 3=bf16 store
template<int EPI>
__global__ __launch_bounds__(256) void mfma_gemm(
    const bf16* __restrict__ A, const bf16* __restrict__ WT,
    const float* __restrict__ bias, float* __restrict__ Cf, bf16* __restrict__ Cb,
    const bf16* __restrict__ zpage)
{
  __shared__ bf16 As[128*64];
  __shared__ bf16 Bs[128*64];
  const int tid = threadIdx.x;
  const int wid = tid >> 6, lane = tid & 63;
  const int wr = wid >> 1, wc = wid & 1;
  const int wg = xcd_swz(blockIdx.x, 750);
  const int bm = (wg / 3) * 128;
  const int bn = (wg % 3) * 128;
  const int srow = lane >> 3;
  const int scolz = swz_st(lane);

  f32x4 acc[4][4] = {};
  for (int ck = 0; ck < 6; ck++){
    const int kk0 = ck * 64;
    __syncthreads();
    #pragma unroll
    for (int s = 0; s < 4; s++){
      int row = wid*32 + s*8 + srow;
      gload16(A + (size_t)(bm + row)*DM + kk0 + scolz, &As[(wid*32 + s*8)*64]);
    }
    #pragma unroll
    for (int s = 0; s < 4; s++){
      int row = wid*32 + s*8 + srow;
      gload16(WT + (size_t)(bn + row)*DM + kk0 + scolz, &Bs[(wid*32 + s*8)*64]);
    }
    __syncthreads();
    #pragma unroll
    for (int ks = 0; ks < 2; ks++){
      const int fo = swz_rd(ks, lane);
      bf16x8 af[4], bg[4];
      #pragma unroll
      for (int m = 0; m < 4; m++)
        af[m] = *(const bf16x8*)&As[(wr*64 + m*16 + (lane & 15))*64 + fo];
      #pragma unroll
      for (int n = 0; n < 4; n++)
        bg[n] = *(const bf16x8*)&Bs[(wc*64 + n*16 + (lane & 15))*64 + fo];
      #pragma unroll
      for (int m = 0; m < 4; m++)
        #pragma unroll
        for (int n = 0; n < 4; n++)
          acc[m][n] = __builtin_amdgcn_mfma_f32_16x16x32_bf16(af[m], bg[n], acc[m][n], 0, 0, 0);
    }
  }
  const int c_l = lane & 15, r4 = (lane >> 4) * 4;
  #pragma unroll
  for (int m = 0; m < 4; m++){
    #pragma unroll
    for (int n = 0; n < 4; n++){
      #pragma unroll
      for (int r = 0; r < 4; r++){
        int token = bm + wr*64 + m*16 + r4 + r;
        int col   = bn + wc*64 + n*16 + c_l;
        float v = acc[m][n][r] + bias[col];
        if (EPI == 0)      Cf[(size_t)token*DM + col] = v;
        else if (EPI == 1) Cf[(size_t)token*DM + col] += v;
        else if (EPI == 2) Cb[(size_t)token*DM + col] = __float2bfloat16(gelu_tanh(v));
        else               Cb[(size_t)token*DM + col] = __float2bfloat16(v);
      }
    }
  }
}

// group-aware conv1 GEMM
template<int EPI, int KIN>
__global__ __launch_bounds__(256) void mfma_c1g(
    const bf16* __restrict__ A, const bf16* __restrict__ WG,
    const float* __restrict__ bias, float* __restrict__ Cf, bf16* __restrict__ Cb,
    const bf16* __restrict__ zpage)
{
  __shared__ bf16 As[128*64];
  __shared__ bf16 Bs[128*64];
  const int tid = threadIdx.x;
  const int wid = tid >> 6, lane = tid & 63;
  const int wr = wid >> 1, wc = wid & 1;
  const int wg = xcd_swz(blockIdx.x, 750);
  const int bm = (wg / 3) * 128;
  const int g  = wg % 3;
  const int srow = lane >> 3;
  const int scolz = swz_st(lane);

  f32x4 acc[4][4] = {};
  for (int ck = 0; ck < 6; ck++){
    const int tap = ck >> 1;
    const int kk0 = (ck & 1) * 64;
    __syncthreads();
    #pragma unroll
    for (int s = 0; s < 4; s++){
      int row = wid*32 + s*8 + srow;
      int token = bm + row;
      int l = token - (token/SEQ)*SEQ;
      int ls = l + tap - 1;
      bool valid = (ls >= 0) && (ls < SEQ);
      const bf16* src = valid ? (A + (size_t)(token + tap - 1)*DM + g*KIN + kk0 + scolz) : zpage;
      gload16(src, &As[(wid*32 + s*8)*64]);
    }
    #pragma unroll
    for (int s = 0; s < 4; s++){
      int row = wid*32 + s*8 + srow;
      gload16(WG + ((size_t)(g*3 + tap)*128 + row)*128 + kk0 + scolz, &Bs[(wid*32 + s*8)*64]);
    }
    __syncthreads();
    #pragma unroll
    for (int ks = 0; ks < 2; ks++){
      const int fo = swz_rd(ks, lane);
      bf16x8 af[4], bg[4];
      #pragma unroll
      for (int m = 0; m < 4; m++)
        af[m] = *(const bf16x8*)&As[(wr*64 + m*16 + (lane & 15))*64 + fo];
      #pragma unroll
      for (int n = 0; n < 4; n++)
        bg[n] = *(const bf16x8*)&Bs[(wc*64 + n*16 + (lane & 15))*64 + fo];
      #pragma unroll
      for (int m = 0; m < 4; m++)
        #pragma unroll
        for (int n = 0; n < 4; n++)
          acc[m][n] = __builtin_amdgcn_mfma_f32_16x16x32_bf16(af[m], bg[n], acc[m][n], 0, 0, 0);
    }
  }
  const int c_l = lane & 15, r4 = (lane >> 4) * 4;
  #pragma unroll
  for (int m = 0; m < 4; m++){
    #pragma unroll
    for (int n = 0; n < 4; n++){
      #pragma unroll
      for (int r = 0; r < 4; r++){
        int token = bm + wr*64 + m*16 + r4 + r;
        int cl    = wc*64 + n*16 + c_l;
        if (EPI == 2){
          if (cl < 114){
            int col = g*114 + cl;
            float v = acc[m][n][r] + bias[col];
            Cb[(size_t)token*DM + col] = __float2bfloat16(gelu_tanh(v));
          }
        } else {
          int col = g*128 + cl;
          float v = acc[m][n][r] + bias[col];
          Cf[(size_t)token*DM + col] += v;
        }
      }
    }
  }
}

// fused Q+K split-bf16 f32-accurate GEMM; 128x64 tile (2x2 waves, 64x32 per wave)
__global__ __launch_bounds__(256) void mfma_qk2(
    const bf16* __restrict__ Ahi, const bf16* __restrict__ Alo,
    const bf16* __restrict__ WqT, const bf16* __restrict__ WkT,
    const float* __restrict__ bq, const float* __restrict__ bk,
    bf16* __restrict__ Qhi, bf16* __restrict__ Qlo,
    bf16* __restrict__ Khi, bf16* __restrict__ Klo)
{
  __shared__ bf16 As[128*64];
  __shared__ bf16 BsQ[64*64];
  __shared__ bf16 BsK[64*64];
  const int tid = threadIdx.x;
  const int wid = tid >> 6, lane = tid & 63;
  const int wr = wid >> 1, wc = wid & 1;
  const int wg = xcd_swz(blockIdx.x, 1500);
  const int bm = (wg / 6) * 128;
  const int bn = (wg % 6) * 64;
  const int srow = lane >> 3;
  const int scolz = swz_st(lane);

  f32x4 accQ[4][2] = {};
  f32x4 accK[4][2] = {};
  for (int kk6 = 0; kk6 < 6; kk6++){
    const int kk0 = kk6 * 64;
    for (int p = 0; p < 3; p++){
      const size_t wo = (p == 1) ? (size_t)DM*DM : 0;
      __syncthreads();
      if (p != 1){
        const bf16* Asrc = (p == 0) ? Ahi : Alo;
        #pragma unroll
        for (int s = 0; s < 4; s++){
          int row = wid*32 + s*8 + srow;
          gload16(Asrc + (size_t)(bm + row)*DM + kk0 + scolz, &As[(wid*32 + s*8)*64]);
        }
      }
      #pragma unroll
      for (int s = 0; s < 2; s++){
        int row = wid*16 + s*8 + srow;
        gload16(WqT + wo + (size_t)(bn + row)*DM + kk0 + scolz, &BsQ[(wid*16 + s*8)*64]);
        gload16(WkT + wo + (size_t)(bn + row)*DM + kk0 + scolz, &BsK[(wid*16 + s*8)*64]);
      }
      __syncthreads();
      #pragma unroll
      for (int ks = 0; ks < 2; ks++){
        const int fo = swz_rd(ks, lane);
        bf16x8 af[4], bgq[2], bgk[2];
        #pragma unroll
        for (int m = 0; m < 4; m++)
          af[m] = *(const bf16x8*)&As[(wr*64 + m*16 + (lane & 15))*64 + fo];
        #pragma unroll
        for (int n = 0; n < 2; n++){
          bgq[n] = *(const bf16x8*)&BsQ[(wc*32 + n*16 + (lane & 15))*64 + fo];
          bgk[n] = *(const bf16x8*)&BsK[(wc*32 + n*16 + (lane & 15))*64 + fo];
        }
        #pragma unroll
        for (int m = 0; m < 4; m++)
          #pragma unroll
          for (int n = 0; n < 2; n++){
            accQ[m][n] = __builtin_amdgcn_mfma_f32_16x16x32_bf16(af[m], bgq[n], accQ[m][n], 0, 0, 0);
            accK[m][n] = __builtin_amdgcn_mfma_f32_16x16x32_bf16(af[m], bgk[n], accK[m][n], 0, 0, 0);
          }
      }
    }
  }
  const int c_l = lane & 15, r4 = (lane >> 4) * 4;
  #pragma unroll
  for (int m = 0; m < 4; m++)
    #pragma unroll
    for (int n = 0; n < 2; n++)
      #pragma unroll
      for (int r = 0; r < 4; r++){
        int token = bm + wr*64 + m*16 + r4 + r;
        int col   = bn + wc*32 + n*16 + c_l;
        size_t off = (size_t)token*DM + col;
        float qv = accQ[m][n][r] + bq[col];
        float kv = accK[m][n][r] + bk[col];
        bf16 qh = __float2bfloat16(qv);
        bf16 kh = __float2bfloat16(kv);
        Qhi[off] = qh; Qlo[off] = __float2bfloat16(qv - __bfloat162float(qh));
        Khi[off] = kh; Klo[off] = __float2bfloat16(kv - __bfloat162float(kh));
      }
}

// ---------------- conv2 as MFMA ----------------
__global__ __launch_bounds__(256) void conv2_mfma(
    const bf16* __restrict__ HT, const bf16* __restrict__ W2T,
    const float* __restrict__ bias, float* __restrict__ X,
    const bf16* __restrict__ zpage)
{
  __shared__ bf16 As[128*64];
  __shared__ bf16 Bs[128*64];
  const int tid = threadIdx.x;
  const int wid = tid >> 6, lane = tid & 63;
  const int wr = wid >> 1, wc = wid & 1;
  const int wg = xcd_swz(blockIdx.x, 768);
  const int bn = (wg % 3) * 128;
  const int g  = (wg / 3) & 1;
  const int b  = wg / 6;
  const int srow = lane >> 3;
  const int scolz = swz_st(lane);
  const bf16* Wbase = W2T + (size_t)g*3*128*128;

  f32x4 acc[4][4] = {};
  for (int ck = 0; ck < 6; ck++){
    const int tap = ck >> 1;
    const int kk0 = (ck & 1) * 64;
    __syncthreads();
    #pragma unroll
    for (int s = 0; s < 4; s++){
      gload16(Wbase + ((size_t)tap*128 + wid*32 + s*8 + srow)*128 + kk0 + scolz, &As[(wid*32 + s*8)*64]);
    }
    #pragma unroll
    for (int s = 0; s < 4; s++){
      int row = wid*32 + s*8 + srow;
      int sd = bn + row + tap - 1;
      const bf16* src = (sd >= 0 && sd < DM)
        ? (HT + (((size_t)b*DM + sd)*2 + g)*128 + kk0 + scolz) : zpage;
      gload16(src, &Bs[(wid*32 + s*8)*64]);
    }
    __syncthreads();
    #pragma unroll
    for (int ks = 0; ks < 2; ks++){
      const int fo = swz_rd(ks, lane);
      bf16x8 af[4], bg[4];
      #pragma unroll
      for (int m = 0; m < 4; m++)
        af[m] = *(const bf16x8*)&As[(wr*64 + m*16 + (lane & 15))*64 + fo];
      #pragma unroll
      for (int n = 0; n < 4; n++)
        bg[n] = *(const bf16x8*)&Bs[(wc*64 + n*16 + (lane & 15))*64 + fo];
      #pragma unroll
      for (int m = 0; m < 4; m++)
        #pragma unroll
        for (int n = 0; n < 4; n++)
          acc[m][n] = __builtin_amdgcn_mfma_f32_16x16x32_bf16(af[m], bg[n], acc[m][n], 0, 0, 0);
    }
  }
  const int c_l = lane & 15, r4 = (lane >> 4) * 4;
  #pragma unroll
  for (int m = 0; m < 4; m++){
    #pragma unroll
    for (int n = 0; n < 4; n++){
      #pragma unroll
      for (int r = 0; r < 4; r++){
        int lo = wr*64 + m*16 + r4 + r;
        if (lo < 125){
          int d = bn + wc*64 + n*16 + c_l;
          float v = acc[m][n][r] + bias[g*125 + lo];
          X[((size_t)b*SEQ + g*125 + lo)*DM + d] += gelu_tanh(v);
        }
      }
    }
  }
}

// ---------------- transpose H[b][l][d] bf16 -> HT[b][d][g*128+li] bf16 ----------------
__global__ __launch_bounds__(256) void transpose_ht(const bf16* __restrict__ H,
                                                    bf16* __restrict__ HT){
  __shared__ bf16 t[68][66];
  int d0 = blockIdx.x * 64;
  int p0 = blockIdx.y * 64;
  int b  = blockIdx.z;
  int tid = threadIdx.x;
  int l0 = p0 - 3;
  for (int i = tid; i < 68*64; i += 256){
    int r = i >> 6, c = i & 63;
    int l = l0 + r;
    bf16 v = __float2bfloat16(0.f);
    if (l >= 0 && l < SEQ) v = H[((size_t)b*SEQ + l)*DM + d0 + c];
    t[r][c] = v;
  }
  __syncthreads();
  for (int i = tid; i < 64*64; i += 256){
    int rr = i >> 6, cc = i & 63;
    int p = p0 + cc;
    int gg = p >> 7, li = p & 127;
    int l = gg*125 + li;
    bf16 v = __float2bfloat16(0.f);
    if (li < 125 && l < SEQ) v = t[l - l0][rr];
    HT[((size_t)b*DM + d0 + rr)*256 + p] = v;
  }
}

// ---------------- weight prep ----------------
__global__ void zfill(bf16* z){ z[threadIdx.x] = __float2bfloat16(0.f); }

__global__ __launch_bounds__(256) void build_projT(const float* __restrict__ Wv,
    const float* __restrict__ Wo, bf16* __restrict__ WvT, bf16* __restrict__ WoT){
  __shared__ float t[32][33];
  int mat = blockIdx.z;
  const float* W = (mat < 4) ? (Wv + (size_t)mat*DM*DM) : (Wo + (size_t)(mat-4)*DM*DM);
  bf16* WT = (mat < 4) ? (WvT + (size_t)mat*DM*DM) : (WoT + (size_t)(mat-4)*DM*DM);
  int k0 = blockIdx.y*32, n0 = blockIdx.x*32;
  int tx = threadIdx.x & 31, ty = threadIdx.x >> 5;
  #pragma unroll
  for (int r = 0; r < 32; r += 8)
    t[ty + r][tx] = W[(size_t)(k0 + ty + r)*DM + n0 + tx];
  __syncthreads();
  #pragma unroll
  for (int r = 0; r < 32; r += 8)
    WT[(size_t)(n0 + ty + r)*DM + k0 + tx] = __float2bfloat16(t[tx][ty + r]);
}

__global__ __launch_bounds__(256) void build_qkhl(const float* __restrict__ Wq,
    const float* __restrict__ Wk, bf16* __restrict__ WT){
  __shared__ float t[32][33];
  int mat = blockIdx.z;
  const float* W = (mat < 4) ? (Wq + (size_t)mat*DM*DM) : (Wk + (size_t)(mat-4)*DM*DM);
  bf16* hi = WT + (size_t)mat*2*DM*DM;
  bf16* lo = hi + (size_t)DM*DM;
  int k0 = blockIdx.y*32, n0 = blockIdx.x*32;
  int tx = threadIdx.x & 31, ty = threadIdx.x >> 5;
  #pragma unroll
  for (int r = 0; r < 32; r += 8)
    t[ty + r][tx] = W[(size_t)(k0 + ty + r)*DM + n0 + tx];
  __syncthreads();
  #pragma unroll
  for (int r = 0; r < 32; r += 8){
    float w = t[tx][ty + r];
    bf16 h = __float2bfloat16(w);
    hi[(size_t)(n0 + ty + r)*DM + k0 + tx] = h;
    lo[(size_t)(n0 + ty + r)*DM + k0 + tx] = __float2bfloat16(w - __bfloat162float(h));
  }
}

__global__ void build_biasA(const float* __restrict__ bin, float* __restrict__ bias_pad){
  int i = blockIdx.x*256 + threadIdx.x;
  if (i >= 4*DM) return;
  int l = i/DM, n = i%DM;
  bias_pad[i] = (n < HID) ? bin[l*HID + n] : 0.f;
}

__global__ void build_c1aG(const float* __restrict__ W, bf16* __restrict__ WG){
  int i = blockIdx.x*256 + threadIdx.x;
  if (i >= 4*3*3*128*128) return;
  int k   = i & 127;
  int n   = (i >> 7) & 127;
  int tap = (i / 16384) % 3;
  int g   = (i / 49152) % 3;
  int l   = i / 147456;
  float v = 0.f;
  if (n < 114)
    v = W[(((size_t)l*HID + g*114 + n)*128 + k)*3 + tap];
  WG[i] = __float2bfloat16(v);
}

__global__ void build_c1bG(const float* __restrict__ W, bf16* __restrict__ WG){
  int i = blockIdx.x*256 + threadIdx.x;
  if (i >= 4*3*3*128*128) return;
  int k   = i & 127;
  int n   = (i >> 7) & 127;
  int tap = (i / 16384) % 3;
  int g   = (i / 49152) % 3;
  int l   = i / 147456;
  float v = 0.f;
  if (k < 114)
    v = W[(((size_t)l*DM + g*128 + n)*114 + k)*3 + tap];
  WG[i] = __float2bfloat16(v);
}

__global__ void build_c2T(const float* __restrict__ W, bf16* __restrict__ WT){
  int i = blockIdx.x*256 + threadIdx.x;
  if (i >= 4*2*3*128*128) return;
  int li = i & 127;
  int lo = (i >> 7) & 127;
  int t  = (i / 16384) % 3;
  int g  = (i / 49152) % 2;
  int l  = i / 98304;
  float v = 0.f;
  if (lo < 125 && li < 125)
    v = W[(((size_t)l*SEQ + g*125 + lo)*125 + li)*3 + t];
  WT[i] = __float2bfloat16(v);
}

// ---------------- fused probe + top-k + attention context per (b,h) ----------------
// V kept OUT of LDS (per-head slice = 24 KB, L2-warm from V-GEMM): vmean streamed
// coalesced from global; PV B-fragments loaded per-lane from global.
// LDS ~48.7 KB -> 3 blocks/CU (was 74 KB -> 2).
static constexpr int SSTR = 260;   // f32 stride
__global__ __launch_bounds__(256) void attn_fused(
    const bf16* __restrict__ Qhi, const bf16* __restrict__ Qlo,
    const bf16* __restrict__ Khi, const bf16* __restrict__ Klo,
    const bf16* __restrict__ V16, const int* __restrict__ idx,
    bf16* __restrict__ CTX, const bf16* __restrict__ zpage)
{
  __shared__ bf16  Qsh[32*64];
  __shared__ bf16  Qsl[32*64];
  __shared__ float Ssh[32*SSTR];
  __shared__ int   IDXsh[32*UU];
  __shared__ float Msh[256];
  __shared__ int   TOPsh[32];
  __shared__ float invsh[32];
  __shared__ float vpart[5][DHd];
  __shared__ float vmean[DHd];
  __shared__ int   mark[SEQ];
  const int bh = xcd_swz(blockIdx.x, Bb*NH);
  const int h = bh & 7; const int b = bh >> 3;
  const int tid = threadIdx.x;
  const int wid = tid >> 6, lane = tid & 63;
  const int scolz = swz_st(lane);
  const size_t base = (size_t)(b*SEQ)*DM + h*DHd;

  // K fragments into VGPRs (once)
  bf16x8 kfh[4][2] = {};
  bf16x8 kfl[4][2] = {};
  {
    const int colb = wid*64 + (lane & 15);
    const int kb   = (lane >> 4) * 8;
    #pragma unroll
    for (int n = 0; n < 4; n++){
      int col = colb + n*16;
      int cc  = (col < SEQ) ? col : (SEQ-1);
      const bf16* ph = Khi + base + (size_t)cc*DM;
      const bf16* pl = Klo + base + (size_t)cc*DM;
      kfh[n][0] = *(const bf16x8*)(ph + kb);
      kfl[n][0] = *(const bf16x8*)(pl + kb);
      if (kb + 32 < DHd){
        kfh[n][1] = *(const bf16x8*)(ph + kb + 32);
        kfl[n][1] = *(const bf16x8*)(pl + kb + 32);
      }
    }
  }
  for (int i = tid; i < SEQ; i += 256) mark[i] = -1;

  const int c_l = lane & 15, r4 = (lane >> 4) * 4;
  // ---- phase 1: probe over 8 Q-tiles ----
  for (int t = 0; t < 8; t++){
    const int r0 = t*32;
    {
      int row = r0 + wid*8 + (lane >> 3);
      bool v = (row < SEQ) && (scolz < DHd);
      const bf16* sh = v ? (Qhi + base + (size_t)row*DM + scolz) : zpage;
      const bf16* sl = v ? (Qlo + base + (size_t)row*DM + scolz) : zpage;
      gload16(sh, &Qsh[(wid*8)*64]);
      gload16(sl, &Qsl[(wid*8)*64]);
    }
    for (int i = tid; i < 32*UU; i += 256){
      int r = i / UU;
      int row = r0 + r;
      IDXsh[i] = (row < SEQ) ? idx[row*UU + (i - r*UU)] : 0;
    }
    __syncthreads();
    f32x4 acc[2][4] = {};
    __builtin_amdgcn_s_setprio(1);
    #pragma unroll
    for (int p = 0; p < 3; p++){
      const bf16* A = (p < 2) ? Qsh : Qsl;
      #pragma unroll
      for (int ks = 0; ks < 2; ks++){
        const int fo = swz_rd(ks, lane);
        bf16x8 af[2];
        #pragma unroll
        for (int m = 0; m < 2; m++)
          af[m] = *(const bf16x8*)&A[(m*16 + (lane & 15))*64 + fo];
        #pragma unroll
        for (int m = 0; m < 2; m++)
          #pragma unroll
          for (int n = 0; n < 4; n++){
            bf16x8 bg = (p == 1) ? kfl[n][ks] : kfh[n][ks];
            acc[m][n] = __builtin_amdgcn_mfma_f32_16x16x32_bf16(af[m], bg, acc[m][n], 0, 0, 0);
          }
      }
    }
    __builtin_amdgcn_s_setprio(0);
    #pragma unroll
    for (int m = 0; m < 2; m++)
      #pragma unroll
      for (int n = 0; n < 4; n++)
        #pragma unroll
        for (int r = 0; r < 4; r++)
          Ssh[(m*16 + r4 + r)*SSTR + wid*64 + n*16 + c_l] = acc[m][n][r];
    __syncthreads();
    {
      int rl = tid >> 3, s8 = tid & 7;
      int row = r0 + rl;
      float mx = -FLT_MAX, sm = 0.f;
      #pragma unroll
      for (int uu = 0; uu < 4; uu++){
        int u = s8 + uu*8;
        if (u < UU){
          int c = IDXsh[rl*UU + u];
          float v = Ssh[rl*SSTR + c];
          mx = fmaxf(mx, v); sm += v;
        }
      }
      #pragma unroll
      for (int off = 4; off; off >>= 1){
        mx = fmaxf(mx, __shfl_xor(mx, off));
        sm += __shfl_xor(sm, off);
      }
      if (s8 == 0 && row < SEQ) Msh[row] = mx - sm*(1.f/UU);
    }
    __syncthreads();
  }
  // ---- top-k (JAX tie-break) into TOPsh — single-wave, barrier-free ----
  if (wid == 0){
    float vals[4]; int ids[4];
    #pragma unroll
    for (int r = 0; r < 4; r++){
      int l = r*64 + lane;
      if (l < SEQ){ vals[r] = Msh[l]; ids[r] = l; }
      else        { vals[r] = -FLT_MAX; ids[r] = 1<<30; }
    }
    for (int sel = 0; sel < UU; sel++){
      float bv = -FLT_MAX; int bi = 1<<30;
      #pragma unroll
      for (int r = 0; r < 4; r++)
        if (vals[r] > bv || (vals[r] == bv && ids[r] < bi)){ bv = vals[r]; bi = ids[r]; }
      #pragma unroll
      for (int off = 32; off; off >>= 1){
        float ov = __shfl_xor(bv, off);
        int   oi = __shfl_xor(bi, off);
        if (ov > bv || (ov == bv && oi < bi)){ bv = ov; bi = oi; }
      }
      if (lane == 0) TOPsh[sel] = bi;
      #pragma unroll
      for (int r = 0; r < 4; r++) if (ids[r] == bi) vals[r] = -FLT_MAX;
    }
  }
  __syncthreads();
  if (tid < UU) mark[TOPsh[tid]] = tid;

  // ---- phase 2: ctx for top-30 rows ----
  {
    int row = wid*8 + (lane >> 3);
    bool v = (row < UU) && (scolz < DHd);
    int tr = v ? TOPsh[row] : 0;
    const bf16* sh = v ? (Qhi + base + (size_t)tr*DM + scolz) : zpage;
    const bf16* sl = v ? (Qlo + base + (size_t)tr*DM + scolz) : zpage;
    gload16(sh, &Qsh[(wid*8)*64]);
    gload16(sl, &Qsl[(wid*8)*64]);
  }
  __syncthreads();
  {
    f32x4 acc[2][4] = {};
    __builtin_amdgcn_s_setprio(1);
    #pragma unroll
    for (int p = 0; p < 3; p++){
      const bf16* A = (p < 2) ? Qsh : Qsl;
      #pragma unroll
      for (int ks = 0; ks < 2; ks++){
        const int fo = swz_rd(ks, lane);
        bf16x8 af[2];
        #pragma unroll
        for (int m = 0; m < 2; m++)
          af[m] = *(const bf16x8*)&A[(m*16 + (lane & 15))*64 + fo];
        #pragma unroll
        for (int m = 0; m < 2; m++)
          #pragma unroll
          for (int n = 0; n < 4; n++){
            bf16x8 bg = (p == 1) ? kfl[n][ks] : kfh[n][ks];
            acc[m][n] = __builtin_amdgcn_mfma_f32_16x16x32_bf16(af[m], bg, acc[m][n], 0, 0, 0);
          }
      }
    }
    __builtin_amdgcn_s_setprio(0);
    #pragma unroll
    for (int m = 0; m < 2; m++)
      #pragma unroll
      for (int n = 0; n < 4; n++)
        #pragma unroll
        for (int r = 0; r < 4; r++)
          Ssh[(m*16 + r4 + r)*SSTR + wid*64 + n*16 + c_l] = acc[m][n][r];
  }
  __syncthreads();
  {
    const float scale = 0.14433756729740643f;
    for (int rr = 0; rr < 8; rr++){
      int row = wid*8 + rr;
      float* Sr = &Ssh[row*SSTR];
      if (row < UU){
        float xs[4];
        #pragma unroll
        for (int j = 0; j < 4; j++){
          int c = lane + 64*j;
          xs[j] = (c < SEQ) ? Sr[c]*scale : -FLT_MAX;
        }
        float mx = fmaxf(fmaxf(xs[0],xs[1]), fmaxf(xs[2],xs[3]));
        #pragma unroll
        for (int off = 32; off; off >>= 1) mx = fmaxf(mx, __shfl_xor(mx, off));
        float sm = 0.f;
        #pragma unroll
        for (int j = 0; j < 4; j++){
          int c = lane + 64*j;
          float e = (c < SEQ) ? expf(xs[j]-mx) : 0.f;
          Sr[c] = e;
          sm += e;
        }
        #pragma unroll
        for (int off = 32; off; off >>= 1) sm += __shfl_xor(sm, off);
        if (lane == 0) invsh[row] = 1.f/sm;
      } else {
        #pragma unroll
        for (int j = 0; j < 4; j++) Sr[lane + 64*j] = 0.f;
      }
    }
    // vmean partials streamed from global V (same 50-token ascending order -> bit-identical)
    if (tid < 240){
      int dh = tid % DHd, pr = tid / DHd;
      const bf16* vp = V16 + base + dh;
      float s = 0.f;
      #pragma unroll 10
      for (int z = 0; z < 50; z++){
        int j = pr*50 + z;
        s += __bfloat162float(vp[(size_t)j*DM]);
      }
      vpart[pr][dh] = s;
    }
  }
  __syncthreads();
  if (tid < DHd)
    vmean[tid] = (vpart[0][tid]+vpart[1][tid]+vpart[2][tid]+vpart[3][tid]+vpart[4][tid]) * (1.f/SEQ);

  if (wid < 3){
    const int dh0 = wid*16;
    const int dh  = dh0 + c_l;
    // hoist all PV B-fragments from global (L1/L2-resident V slice)
    bf16x8 bvv[8];
    #pragma unroll
    for (int kc = 0; kc < 8; kc++){
      int j0 = kc*32 + (lane >> 4)*8;
      #pragma unroll
      for (int i = 0; i < 8; i++){
        int j = j0 + i;
        bf16 vv = (j < SEQ) ? V16[base + (size_t)j*DM + dh] : __float2bfloat16(0.f);
        bvv[kc][i] = *reinterpret_cast<short*>(&vv);
      }
    }
    f32x4 acc2[2] = {};
    __builtin_amdgcn_s_setprio(1);
    for (int kc = 0; kc < 8; kc++){
      #pragma unroll
      for (int m = 0; m < 2; m++){
        const float* pr = &Ssh[(m*16 + (lane & 15))*SSTR + kc*32 + (lane >> 4)*8];
        bf16x8 pa;
        #pragma unroll
        for (int i = 0; i < 8; i++){
          bf16 hh = __float2bfloat16(pr[i]);
          pa[i] = *reinterpret_cast<short*>(&hh);
        }
        acc2[m] = __builtin_amdgcn_mfma_f32_16x16x32_bf16(pa, bvv[kc], acc2[m], 0, 0, 0);
      }
    }
    __builtin_amdgcn_s_setprio(0);
    #pragma unroll
    for (int m = 0; m < 2; m++)
      #pragma unroll
      for (int r = 0; r < 4; r++){
        int u = m*16 + r4 + r;
        if (u < UU){
          float val = acc2[m][r] * invsh[u];
          CTX[(size_t)(b*SEQ + TOPsh[u])*DM + h*DHd + dh0 + c_l] = __float2bfloat16(val);
        }
      }
  }
  __syncthreads();
  for (int i = tid; i < SEQ*DHd; i += 256){
    int l = i / DHd, dh = i - l*DHd;
    if (mark[l] < 0)
      CTX[(size_t)(b*SEQ + l)*DM + h*DHd + dh] = __float2bfloat16(vmean[dh]);
  }
}

// ---------------- final: max over L -> LN(ln2) -> FC ----------------
__global__ __launch_bounds__(384) void final_kernel(const float* __restrict__ Hin,
    const float* __restrict__ w, const float* __restrict__ bparm,
    const float* __restrict__ fcw, const float* __restrict__ fcb, float* __restrict__ out){
  __shared__ float red[8];
  __shared__ float ybuf[DM];
  int b = blockIdx.x; int d = threadIdx.x;
  const float* hp = Hin + (size_t)b*SEQ*DM + d;
  float mx = -FLT_MAX;
  for (int l=0;l<SEQ;l++) mx = fmaxf(mx, hp[(size_t)l*DM]);
  float mu = block_sum(mx, red) * (1.f/DM);
  float diff = mx - mu;
  float var = block_sum(diff*diff, red) * (1.f/DM);
  float y = diff * rsqrtf(var + 1e-5f) * w[d] + bparm[d];
  ybuf[d] = y;
  __syncthreads();
  if (d < 10){
    float acc = fcb[d];
    for (int k=0;k<DM;k++) acc += ybuf[k] * fcw[k*10 + d];
    out[b*10 + d] = acc;
  }
}

// ---------------- host orchestration ----------------
extern "C" void kernel_launch(void* const* d_in, const int* in_sizes, int n_in,
                              void* d_out, int out_size, void* d_ws, size_t ws_size,
                              hipStream_t stream) {
  const float* x     = (const float*)d_in[0];
  const float* pos   = (const float*)d_in[1];
  const float* lniw  = (const float*)d_in[2];
  const float* lnib  = (const float*)d_in[3];
  const float* lnAw  = (const float*)d_in[4];
  const float* lnAb  = (const float*)d_in[5];
  const float* Wq    = (const float*)d_in[6];
  const float* bq    = (const float*)d_in[7];
  const float* Wk    = (const float*)d_in[8];
  const float* bk    = (const float*)d_in[9];
  const float* Wv    = (const float*)d_in[10];
  const float* bv    = (const float*)d_in[11];
  const float* Wo    = (const float*)d_in[12];
  const float* bo    = (const float*)d_in[13];
  const float* lnBw  = (const float*)d_in[14];
  const float* lnBb  = (const float*)d_in[15];
  const float* c1aw  = (const float*)d_in[16];
  const float* c1ab  = (const float*)d_in[17];
  const float* c1bw  = (const float*)d_in[18];
  const float* c1bb  = (const float*)d_in[19];
  const float* lnCw  = (const float*)d_in[20];
  const float* lnCb  = (const float*)d_in[21];
  const float* c2w   = (const float*)d_in[22];
  const float* c2b   = (const float*)d_in[23];
  const float* ln2w  = (const float*)d_in[24];
  const float* ln2b  = (const float*)d_in[25];
  const float* fcw   = (const float*)d_in[26];
  const float* fcb   = (const float*)d_in[27];
  float* out = (float*)d_out;

  const size_t ACT  = (size_t)Bb*SEQ*DM;        // 12,288,000
  float* Xb  = (float*)d_ws;
  float* Hb  = Xb  + ACT;
  float* Qb  = Hb  + ACT;
  float* Kb  = Qb  + ACT;
  float* Vb  = Kb  + ACT;
  float* biasA = Vb + ACT;
  int*   TOP = (int*)(biasA + 4*DM);            // unused (layout stability)
  int*   IDX = TOP + (size_t)Bb*NH*UU;
  bf16*  Hb16 = (bf16*)(IDX + 4*7500);
  bf16*  G1   = Hb16 + ACT;
  bf16*  WvT  = G1   + ACT;
  bf16*  WoT  = WvT  + (size_t)4*DM*DM;
  bf16*  WaG  = WoT  + (size_t)4*DM*DM;
  bf16*  WbG  = WaG  + (size_t)12*DM*DM;
  bf16*  WqkT = WbG  + (size_t)12*DM*DM;
  bf16*  W2T  = WqkT + (size_t)16*DM*DM;
  bf16*  zp   = W2T  + (size_t)4*2*3*128*128;

  bf16* Qhi = (bf16*)Qb; bf16* Qlo = Qhi + ACT;
  bf16* Khi = (bf16*)Kb; bf16* Klo = Khi + ACT;
  bf16* V16 = (bf16*)Vb;

  zfill<<<dim3(1), dim3(256), 0, stream>>>(zp);
  hipMemsetAsync(G1, 0, ACT*sizeof(bf16), stream);
  idx_kernel<<<dim3(118), dim3(256), 0, stream>>>(IDX);
  build_projT<<<dim3(12,12,8), dim3(256), 0, stream>>>(Wv, Wo, WvT, WoT);
  build_qkhl<<<dim3(12,12,8), dim3(256), 0, stream>>>(Wq, Wk, WqkT);
  build_biasA<<<dim3(6), dim3(256), 0, stream>>>(c1ab, biasA);
  build_c1aG<<<dim3(2304), dim3(256), 0, stream>>>(c1aw, WaG);
  build_c1bG<<<dim3(2304), dim3(256), 0, stream>>>(c1bw, WbG);
  build_c2T<<<dim3(1536), dim3(256), 0, stream>>>(c2w, W2T);
  pool_ln_pos<<<dim3(32000), dim3(384), 0, stream>>>(x, pos, lniw, lnib, Xb);

  for (int l = 0; l < 4; l++){
    const size_t wofs = (size_t)l*DM*DM;
    bf16* Alo16 = (bf16*)Hb;
    bf16* CTX16 = Hb16;
    bf16* HTb   = (bf16*)Qb;
    ln_wave<2><<<dim3(8000), dim3(256), 0, stream>>>(Xb, (float*)nullptr, Hb16, Alo16, lnAw + l*DM, lnAb + l*DM);
    mfma_qk2<<<dim3(1500), dim3(256), 0, stream>>>(Hb16, Alo16,
        WqkT + (size_t)l*2*DM*DM, WqkT + (size_t)(4+l)*2*DM*DM,
        bq + l*DM, bk + l*DM, Qhi, Qlo, Khi, Klo);
    mfma_gemm<3><<<dim3(750), dim3(256), 0, stream>>>(Hb16, WvT + wofs, bv + l*DM, (float*)nullptr, V16, zp);
    attn_fused<<<dim3(Bb*NH), dim3(256), 0, stream>>>(Qhi, Qlo, Khi, Klo, V16, IDX + l*7500, CTX16, zp);
    mfma_gemm<1><<<dim3(750), dim3(256), 0, stream>>>(CTX16, WoT + wofs, bo + l*DM, Xb, (bf16*)nullptr, zp);

    ln_wave<1><<<dim3(8000), dim3(256), 0, stream>>>(Xb, (float*)nullptr, Hb16, (bf16*)nullptr, lnBw + l*DM, lnBb + l*DM);
    mfma_c1g<2,128><<<dim3(750), dim3(256), 0, stream>>>(Hb16, WaG + (size_t)l*3*3*128*128, biasA + l*DM, (float*)nullptr, G1, zp);
    mfma_c1g<1,114><<<dim3(750), dim3(256), 0, stream>>>(G1, WbG + (size_t)l*3*3*128*128, c1bb + l*DM, Xb, (bf16*)nullptr, zp);

    ln_wave<1><<<dim3(8000), dim3(256), 0, stream>>>(Xb, (float*)nullptr, Hb16, (bf16*)nullptr, lnCw + l*DM, lnCb + l*DM);
    transpose_ht<<<dim3(6,4,Bb), dim3(256), 0, stream>>>(Hb16, HTb);
    conv2_mfma<<<dim3(768), dim3(256), 0, stream>>>(HTb, W2T + (size_t)l*2*3*128*128, c2b + l*SEQ, Xb, zp);
  }

  ln_wave<0><<<dim3(8000), dim3(256), 0, stream>>>(Xb, Hb, (bf16*)nullptr, (bf16*)nullptr, ln2w, ln2b);
  final_kernel<<<dim3(Bb), dim3(384), 0, stream>>>(Hb, ln2w, ln2b, fcw, fcb, out);
}

// Round 24
// 1891.564 us; speedup vs baseline: 1.1388x; 1.0522x over previous
//
#include <hip/hip_runtime.h>
#include <hip/hip_bf16.h>
#include <cfloat>
#include <cstdint>

// ---------------- constants ----------------
static constexpr int Bb   = 128;
static constexpr int SEQ  = 250;
static constexpr int DM   = 384;
static constexpr int NH   = 8;
static constexpr int DHd  = 48;
static constexpr int HID  = 342;
static constexpr int UU   = 30;   // U == u == 30

using bf16 = __hip_bfloat16;
typedef __attribute__((ext_vector_type(8))) short bf16x8;
typedef __attribute__((ext_vector_type(4))) float f32x4;

__device__ __forceinline__ float unpk_lo(uint32_t p){ return __builtin_bit_cast(float, p << 16); }
__device__ __forceinline__ float unpk_hi(uint32_t p){ return __builtin_bit_cast(float, p & 0xffff0000u); }

// LDS XOR swizzle for [row][64 bf16] tiles (128B rows), global_load_lds-compatible.
__device__ __forceinline__ int swz_st(int lane){ return (((lane & 7) ^ (lane >> 3)) << 3); }
__device__ __forceinline__ int swz_rd(int ks, int lane){ return ((((ks<<2) + (lane >> 4)) ^ (lane & 7)) << 3); }

// bijective XCD-aware block remap (m204 formula)
__device__ __forceinline__ int xcd_swz(int orig, int nwg){
  int q = nwg >> 3, r = nwg & 7;
  int x = orig & 7, i = orig >> 3;
  int start = (x < r) ? x*(q+1) : r*(q+1) + (x-r)*q;
  return start + i;
}

// ---------------- threefry2x32 (JAX-exact) ----------------
__device__ __forceinline__ uint32_t rotl32(uint32_t x, int n){ return (x<<n)|(x>>(32-n)); }
#define TF_R(x0,x1,r) { x0 += x1; x1 = rotl32(x1,(r)); x1 ^= x0; }
__device__ inline void threefry(uint32_t k0, uint32_t k1, uint32_t x0, uint32_t x1,
                                uint32_t &o0, uint32_t &o1){
  uint32_t ks2 = k0 ^ k1 ^ 0x1BD11BDAu;
  x0 += k0; x1 += k1;
  TF_R(x0,x1,13) TF_R(x0,x1,15) TF_R(x0,x1,26) TF_R(x0,x1,6)
  x0 += k1; x1 += ks2 + 1u;
  TF_R(x0,x1,17) TF_R(x0,x1,29) TF_R(x0,x1,16) TF_R(x0,x1,24)
  x0 += ks2; x1 += k0 + 2u;
  TF_R(x0,x1,13) TF_R(x0,x1,15) TF_R(x0,x1,26) TF_R(x0,x1,6)
  x0 += k0; x1 += k1 + 3u;
  TF_R(x0,x1,17) TF_R(x0,x1,29) TF_R(x0,x1,16) TF_R(x0,x1,24)
  x0 += k1; x1 += ks2 + 4u;
  TF_R(x0,x1,13) TF_R(x0,x1,15) TF_R(x0,x1,26) TF_R(x0,x1,6)
  x0 += ks2; x1 += k0 + 5u;
  o0 = x0; o1 = x1;
}

__global__ void idx_kernel(int* __restrict__ IDX){
  int i = blockIdx.x*256 + threadIdx.x;
  if (i >= 4*7500) return;
  int l = i / 7500;
  int t = i % 7500;
  uint32_t fk0, fk1;
  threefry(0u, 42u, 0u, (uint32_t)l, fk0, fk1);
  uint32_t a0,a1,b0,b1;
  threefry(fk0, fk1, 0u, 2u, a0, a1);
  threefry(fk0, fk1, 1u, 3u, b0, b1);
  uint32_t c0 = (t < 3750) ? (uint32_t)t          : (uint32_t)(t-3750);
  uint32_t c1 = (t < 3750) ? (uint32_t)(t+3750)   : (uint32_t)t;
  uint32_t y0, y1, hi, lo;
  threefry(a0, b0, c0, c1, y0, y1); hi = (t < 3750) ? y0 : y1;
  threefry(a1, b1, c0, c1, y0, y1); lo = (t < 3750) ? y0 : y1;
  uint32_t val = ((hi % 250u) * 46u + (lo % 250u)) % 250u;
  IDX[i] = (int)val;
}

// ---------------- block reductions (used by pool/final) ----------------
__device__ __forceinline__ float block_sum(float v, float* red){
  v += __shfl_down(v,32); v += __shfl_down(v,16); v += __shfl_down(v,8);
  v += __shfl_down(v,4);  v += __shfl_down(v,2);  v += __shfl_down(v,1);
  int lane = threadIdx.x & 63, wid = threadIdx.x >> 6, nw = blockDim.x >> 6;
  __syncthreads();
  if (lane == 0) red[wid] = v;
  __syncthreads();
  float r = red[0];
  for (int i=1;i<nw;i++) r += red[i];
  return r;
}

// fast gelu (tanh form) via sigmoid identity: 0.5x(1+tanh(t)) = x * sigmoid(2t)
// robust at tails: t->+inf => x ; t->-inf => x/inf = 0
__device__ __forceinline__ float gelu_tanh(float x){
  float t = 0.7978845608028654f * (x + 0.044715f * x * x * x);
  return x / (1.f + __expf(-2.f * t));
}

// ---------------- pool (max over 4) + LN + pos ----------------
__global__ __launch_bounds__(384) void pool_ln_pos(const float* __restrict__ xin,
    const float* __restrict__ pos, const float* __restrict__ w, const float* __restrict__ b,
    float* __restrict__ X){
  __shared__ float red[8];
  int bs = blockIdx.x; int bb = bs / SEQ, s = bs % SEQ; int d = threadIdx.x;
  const float* xp = xin + ((size_t)bb*1000 + (size_t)s*4)*DM + d;
  float v = fmaxf(fmaxf(xp[0], xp[DM]), fmaxf(xp[2*DM], xp[3*DM]));
  float mu = block_sum(v, red) * (1.f/DM);
  float diff = v - mu;
  float var = block_sum(diff*diff, red) * (1.f/DM);
  X[(size_t)bs*DM + d] = diff * rsqrtf(var + 1e-5f) * w[d] + b[d] + pos[(size_t)s*DM + d];
}

// ---------------- wave-per-row LayerNorm ----------------
template<int MODE>
__global__ __launch_bounds__(256) void ln_wave(const float* __restrict__ in,
    float* __restrict__ o32, bf16* __restrict__ o16, bf16* __restrict__ olo,
    const float* __restrict__ w, const float* __restrict__ b){
  size_t row = (size_t)blockIdx.x*4 + (threadIdx.x >> 6);
  int lane = threadIdx.x & 63;
  const float* rp = in + row*DM;
  float v[6];
  #pragma unroll
  for (int i = 0; i < 6; i++) v[i] = rp[lane + 64*i];
  float s = v[0]+v[1]+v[2]+v[3]+v[4]+v[5];
  #pragma unroll
  for (int off = 32; off; off >>= 1) s += __shfl_xor(s, off);
  float mu = s * (1.f/DM);
  float q = 0.f;
  #pragma unroll
  for (int i = 0; i < 6; i++){ float d = v[i]-mu; q += d*d; }
  #pragma unroll
  for (int off = 32; off; off >>= 1) q += __shfl_xor(q, off);
  float rs = rsqrtf(q*(1.f/DM) + 1e-5f);
  #pragma unroll
  for (int i = 0; i < 6; i++){
    int d = lane + 64*i;
    float y = (v[i]-mu)*rs*w[d] + b[d];
    if (MODE == 0) o32[row*DM + d] = y;
    if (MODE == 1) o16[row*DM + d] = __float2bfloat16(y);
    if (MODE == 2){
      bf16 h = __float2bfloat16(y);
      o16[row*DM + d] = h;
      olo[row*DM + d] = __float2bfloat16(y - __bfloat162float(h));
    }
  }
}

// ---------------- bf16 MFMA GEMM ----------------
__device__ __forceinline__ void gload16(const void* g, void* l){
  __builtin_amdgcn_global_load_lds(
      (__attribute__((address_space(1))) void*)(g),
      (__attribute__((address_space(3))) void*)(l), 16, 0, 0);
}

// Dense GEMM: C[M x 384] = A @ W ; EPI: 0=f32 store 1=f32 += 2=bf16 gelu 3=bf16 store
template<int EPI>
__global__ __launch_bounds__(256) void mfma_gemm(
    const bf16* __restrict__ A, const bf16* __restrict__ WT,
    const float* __restrict__ bias, float* __restrict__ Cf, bf16* __restrict__ Cb,
    const bf16* __restrict__ zpage)
{
  __shared__ bf16 As[128*64];
  __shared__ bf16 Bs[128*64];
  const int tid = threadIdx.x;
  const int wid = tid >> 6, lane = tid & 63;
  const int wr = wid >> 1, wc = wid & 1;
  const int wg = xcd_swz(blockIdx.x, 750);
  const int bm = (wg / 3) * 128;
  const int bn = (wg % 3) * 128;
  const int srow = lane >> 3;
  const int scolz = swz_st(lane);

  f32x4 acc[4][4] = {};
  for (int ck = 0; ck < 6; ck++){
    const int kk0 = ck * 64;
    __syncthreads();
    #pragma unroll
    for (int s = 0; s < 4; s++){
      int row = wid*32 + s*8 + srow;
      gload16(A + (size_t)(bm + row)*DM + kk0 + scolz, &As[(wid*32 + s*8)*64]);
    }
    #pragma unroll
    for (int s = 0; s < 4; s++){
      int row = wid*32 + s*8 + srow;
      gload16(WT + (size_t)(bn + row)*DM + kk0 + scolz, &Bs[(wid*32 + s*8)*64]);
    }
    __syncthreads();
    #pragma unroll
    for (int ks = 0; ks < 2; ks++){
      const int fo = swz_rd(ks, lane);
      bf16x8 af[4], bg[4];
      #pragma unroll
      for (int m = 0; m < 4; m++)
        af[m] = *(const bf16x8*)&As[(wr*64 + m*16 + (lane & 15))*64 + fo];
      #pragma unroll
      for (int n = 0; n < 4; n++)
        bg[n] = *(const bf16x8*)&Bs[(wc*64 + n*16 + (lane & 15))*64 + fo];
      #pragma unroll
      for (int m = 0; m < 4; m++)
        #pragma unroll
        for (int n = 0; n < 4; n++)
          acc[m][n] = __builtin_amdgcn_mfma_f32_16x16x32_bf16(af[m], bg[n], acc[m][n], 0, 0, 0);
    }
  }
  const int c_l = lane & 15, r4 = (lane >> 4) * 4;
  #pragma unroll
  for (int m = 0; m < 4; m++){
    #pragma unroll
    for (int n = 0; n < 4; n++){
      #pragma unroll
      for (int r = 0; r < 4; r++){
        int token = bm + wr*64 + m*16 + r4 + r;
        int col   = bn + wc*64 + n*16 + c_l;
        float v = acc[m][n][r] + bias[col];
        if (EPI == 0)      Cf[(size_t)token*DM + col] = v;
        else if (EPI == 1) Cf[(size_t)token*DM + col] += v;
        else if (EPI == 2) Cb[(size_t)token*DM + col] = __float2bfloat16(gelu_tanh(v));
        else               Cb[(size_t)token*DM + col] = __float2bfloat16(v);
      }
    }
  }
}

// group-aware conv1 GEMM
template<int EPI, int KIN>
__global__ __launch_bounds__(256) void mfma_c1g(
    const bf16* __restrict__ A, const bf16* __restrict__ WG,
    const float* __restrict__ bias, float* __restrict__ Cf, bf16* __restrict__ Cb,
    const bf16* __restrict__ zpage)
{
  __shared__ bf16 As[128*64];
  __shared__ bf16 Bs[128*64];
  const int tid = threadIdx.x;
  const int wid = tid >> 6, lane = tid & 63;
  const int wr = wid >> 1, wc = wid & 1;
  const int wg = xcd_swz(blockIdx.x, 750);
  const int bm = (wg / 3) * 128;
  const int g  = wg % 3;
  const int srow = lane >> 3;
  const int scolz = swz_st(lane);

  f32x4 acc[4][4] = {};
  for (int ck = 0; ck < 6; ck++){
    const int tap = ck >> 1;
    const int kk0 = (ck & 1) * 64;
    __syncthreads();
    #pragma unroll
    for (int s = 0; s < 4; s++){
      int row = wid*32 + s*8 + srow;
      int token = bm + row;
      int l = token - (token/SEQ)*SEQ;
      int ls = l + tap - 1;
      bool valid = (ls >= 0) && (ls < SEQ);
      const bf16* src = valid ? (A + (size_t)(token + tap - 1)*DM + g*KIN + kk0 + scolz) : zpage;
      gload16(src, &As[(wid*32 + s*8)*64]);
    }
    #pragma unroll
    for (int s = 0; s < 4; s++){
      int row = wid*32 + s*8 + srow;
      gload16(WG + ((size_t)(g*3 + tap)*128 + row)*128 + kk0 + scolz, &Bs[(wid*32 + s*8)*64]);
    }
    __syncthreads();
    #pragma unroll
    for (int ks = 0; ks < 2; ks++){
      const int fo = swz_rd(ks, lane);
      bf16x8 af[4], bg[4];
      #pragma unroll
      for (int m = 0; m < 4; m++)
        af[m] = *(const bf16x8*)&As[(wr*64 + m*16 + (lane & 15))*64 + fo];
      #pragma unroll
      for (int n = 0; n < 4; n++)
        bg[n] = *(const bf16x8*)&Bs[(wc*64 + n*16 + (lane & 15))*64 + fo];
      #pragma unroll
      for (int m = 0; m < 4; m++)
        #pragma unroll
        for (int n = 0; n < 4; n++)
          acc[m][n] = __builtin_amdgcn_mfma_f32_16x16x32_bf16(af[m], bg[n], acc[m][n], 0, 0, 0);
    }
  }
  const int c_l = lane & 15, r4 = (lane >> 4) * 4;
  #pragma unroll
  for (int m = 0; m < 4; m++){
    #pragma unroll
    for (int n = 0; n < 4; n++){
      #pragma unroll
      for (int r = 0; r < 4; r++){
        int token = bm + wr*64 + m*16 + r4 + r;
        int cl    = wc*64 + n*16 + c_l;
        if (EPI == 2){
          if (cl < 114){
            int col = g*114 + cl;
            float v = acc[m][n][r] + bias[col];
            Cb[(size_t)token*DM + col] = __float2bfloat16(gelu_tanh(v));
          }
        } else {
          int col = g*128 + cl;
          float v = acc[m][n][r] + bias[col];
          Cf[(size_t)token*DM + col] += v;
        }
      }
    }
  }
}

// fused Q+K split-bf16 f32-accurate GEMM; 128x64 tile (2x2 waves, 64x32 per wave)
__global__ __launch_bounds__(256) void mfma_qk2(
    const bf16* __restrict__ Ahi, const bf16* __restrict__ Alo,
    const bf16* __restrict__ WqT, const bf16* __restrict__ WkT,
    const float* __restrict__ bq, const float* __restrict__ bk,
    bf16* __restrict__ Qhi, bf16* __restrict__ Qlo,
    bf16* __restrict__ Khi, bf16* __restrict__ Klo)
{
  __shared__ bf16 As[128*64];
  __shared__ bf16 BsQ[64*64];
  __shared__ bf16 BsK[64*64];
  const int tid = threadIdx.x;
  const int wid = tid >> 6, lane = tid & 63;
  const int wr = wid >> 1, wc = wid & 1;
  const int wg = xcd_swz(blockIdx.x, 1500);
  const int bm = (wg / 6) * 128;
  const int bn = (wg % 6) * 64;
  const int srow = lane >> 3;
  const int scolz = swz_st(lane);

  f32x4 accQ[4][2] = {};
  f32x4 accK[4][2] = {};
  for (int kk6 = 0; kk6 < 6; kk6++){
    const int kk0 = kk6 * 64;
    for (int p = 0; p < 3; p++){
      const size_t wo = (p == 1) ? (size_t)DM*DM : 0;
      __syncthreads();
      if (p != 1){
        const bf16* Asrc = (p == 0) ? Ahi : Alo;
        #pragma unroll
        for (int s = 0; s < 4; s++){
          int row = wid*32 + s*8 + srow;
          gload16(Asrc + (size_t)(bm + row)*DM + kk0 + scolz, &As[(wid*32 + s*8)*64]);
        }
      }
      #pragma unroll
      for (int s = 0; s < 2; s++){
        int row = wid*16 + s*8 + srow;
        gload16(WqT + wo + (size_t)(bn + row)*DM + kk0 + scolz, &BsQ[(wid*16 + s*8)*64]);
        gload16(WkT + wo + (size_t)(bn + row)*DM + kk0 + scolz, &BsK[(wid*16 + s*8)*64]);
      }
      __syncthreads();
      #pragma unroll
      for (int ks = 0; ks < 2; ks++){
        const int fo = swz_rd(ks, lane);
        bf16x8 af[4], bgq[2], bgk[2];
        #pragma unroll
        for (int m = 0; m < 4; m++)
          af[m] = *(const bf16x8*)&As[(wr*64 + m*16 + (lane & 15))*64 + fo];
        #pragma unroll
        for (int n = 0; n < 2; n++){
          bgq[n] = *(const bf16x8*)&BsQ[(wc*32 + n*16 + (lane & 15))*64 + fo];
          bgk[n] = *(const bf16x8*)&BsK[(wc*32 + n*16 + (lane & 15))*64 + fo];
        }
        #pragma unroll
        for (int m = 0; m < 4; m++)
          #pragma unroll
          for (int n = 0; n < 2; n++){
            accQ[m][n] = __builtin_amdgcn_mfma_f32_16x16x32_bf16(af[m], bgq[n], accQ[m][n], 0, 0, 0);
            accK[m][n] = __builtin_amdgcn_mfma_f32_16x16x32_bf16(af[m], bgk[n], accK[m][n], 0, 0, 0);
          }
      }
    }
  }
  const int c_l = lane & 15, r4 = (lane >> 4) * 4;
  #pragma unroll
  for (int m = 0; m < 4; m++)
    #pragma unroll
    for (int n = 0; n < 2; n++)
      #pragma unroll
      for (int r = 0; r < 4; r++){
        int token = bm + wr*64 + m*16 + r4 + r;
        int col   = bn + wc*32 + n*16 + c_l;
        size_t off = (size_t)token*DM + col;
        float qv = accQ[m][n][r] + bq[col];
        float kv = accK[m][n][r] + bk[col];
        bf16 qh = __float2bfloat16(qv);
        bf16 kh = __float2bfloat16(kv);
        Qhi[off] = qh; Qlo[off] = __float2bfloat16(qv - __bfloat162float(qh));
        Khi[off] = kh; Klo[off] = __float2bfloat16(kv - __bfloat162float(kh));
      }
}

// ---------------- conv2 as MFMA ----------------
__global__ __launch_bounds__(256) void conv2_mfma(
    const bf16* __restrict__ HT, const bf16* __restrict__ W2T,
    const float* __restrict__ bias, float* __restrict__ X,
    const bf16* __restrict__ zpage)
{
  __shared__ bf16 As[128*64];
  __shared__ bf16 Bs[128*64];
  const int tid = threadIdx.x;
  const int wid = tid >> 6, lane = tid & 63;
  const int wr = wid >> 1, wc = wid & 1;
  const int wg = xcd_swz(blockIdx.x, 768);
  const int bn = (wg % 3) * 128;
  const int g  = (wg / 3) & 1;
  const int b  = wg / 6;
  const int srow = lane >> 3;
  const int scolz = swz_st(lane);
  const bf16* Wbase = W2T + (size_t)g*3*128*128;

  f32x4 acc[4][4] = {};
  for (int ck = 0; ck < 6; ck++){
    const int tap = ck >> 1;
    const int kk0 = (ck & 1) * 64;
    __syncthreads();
    #pragma unroll
    for (int s = 0; s < 4; s++){
      gload16(Wbase + ((size_t)tap*128 + wid*32 + s*8 + srow)*128 + kk0 + scolz, &As[(wid*32 + s*8)*64]);
    }
    #pragma unroll
    for (int s = 0; s < 4; s++){
      int row = wid*32 + s*8 + srow;
      int sd = bn + row + tap - 1;
      const bf16* src = (sd >= 0 && sd < DM)
        ? (HT + (((size_t)b*DM + sd)*2 + g)*128 + kk0 + scolz) : zpage;
      gload16(src, &Bs[(wid*32 + s*8)*64]);
    }
    __syncthreads();
    #pragma unroll
    for (int ks = 0; ks < 2; ks++){
      const int fo = swz_rd(ks, lane);
      bf16x8 af[4], bg[4];
      #pragma unroll
      for (int m = 0; m < 4; m++)
        af[m] = *(const bf16x8*)&As[(wr*64 + m*16 + (lane & 15))*64 + fo];
      #pragma unroll
      for (int n = 0; n < 4; n++)
        bg[n] = *(const bf16x8*)&Bs[(wc*64 + n*16 + (lane & 15))*64 + fo];
      #pragma unroll
      for (int m = 0; m < 4; m++)
        #pragma unroll
        for (int n = 0; n < 4; n++)
          acc[m][n] = __builtin_amdgcn_mfma_f32_16x16x32_bf16(af[m], bg[n], acc[m][n], 0, 0, 0);
    }
  }
  const int c_l = lane & 15, r4 = (lane >> 4) * 4;
  #pragma unroll
  for (int m = 0; m < 4; m++){
    #pragma unroll
    for (int n = 0; n < 4; n++){
      #pragma unroll
      for (int r = 0; r < 4; r++){
        int lo = wr*64 + m*16 + r4 + r;
        if (lo < 125){
          int d = bn + wc*64 + n*16 + c_l;
          float v = acc[m][n][r] + bias[g*125 + lo];
          X[((size_t)b*SEQ + g*125 + lo)*DM + d] += gelu_tanh(v);
        }
      }
    }
  }
}

// ---------------- transpose H[b][l][d] bf16 -> HT[b][d][g*128+li] bf16 ----------------
__global__ __launch_bounds__(256) void transpose_ht(const bf16* __restrict__ H,
                                                    bf16* __restrict__ HT){
  __shared__ bf16 t[68][66];
  int d0 = blockIdx.x * 64;
  int p0 = blockIdx.y * 64;
  int b  = blockIdx.z;
  int tid = threadIdx.x;
  int l0 = p0 - 3;
  for (int i = tid; i < 68*64; i += 256){
    int r = i >> 6, c = i & 63;
    int l = l0 + r;
    bf16 v = __float2bfloat16(0.f);
    if (l >= 0 && l < SEQ) v = H[((size_t)b*SEQ + l)*DM + d0 + c];
    t[r][c] = v;
  }
  __syncthreads();
  for (int i = tid; i < 64*64; i += 256){
    int rr = i >> 6, cc = i & 63;
    int p = p0 + cc;
    int gg = p >> 7, li = p & 127;
    int l = gg*125 + li;
    bf16 v = __float2bfloat16(0.f);
    if (li < 125 && l < SEQ) v = t[l - l0][rr];
    HT[((size_t)b*DM + d0 + rr)*256 + p] = v;
  }
}

// ---------------- weight prep ----------------
__global__ void zfill(bf16* z){ z[threadIdx.x] = __float2bfloat16(0.f); }

__global__ __launch_bounds__(256) void build_projT(const float* __restrict__ Wv,
    const float* __restrict__ Wo, bf16* __restrict__ WvT, bf16* __restrict__ WoT){
  __shared__ float t[32][33];
  int mat = blockIdx.z;
  const float* W = (mat < 4) ? (Wv + (size_t)mat*DM*DM) : (Wo + (size_t)(mat-4)*DM*DM);
  bf16* WT = (mat < 4) ? (WvT + (size_t)mat*DM*DM) : (WoT + (size_t)(mat-4)*DM*DM);
  int k0 = blockIdx.y*32, n0 = blockIdx.x*32;
  int tx = threadIdx.x & 31, ty = threadIdx.x >> 5;
  #pragma unroll
  for (int r = 0; r < 32; r += 8)
    t[ty + r][tx] = W[(size_t)(k0 + ty + r)*DM + n0 + tx];
  __syncthreads();
  #pragma unroll
  for (int r = 0; r < 32; r += 8)
    WT[(size_t)(n0 + ty + r)*DM + k0 + tx] = __float2bfloat16(t[tx][ty + r]);
}

__global__ __launch_bounds__(256) void build_qkhl(const float* __restrict__ Wq,
    const float* __restrict__ Wk, bf16* __restrict__ WT){
  __shared__ float t[32][33];
  int mat = blockIdx.z;
  const float* W = (mat < 4) ? (Wq + (size_t)mat*DM*DM) : (Wk + (size_t)(mat-4)*DM*DM);
  bf16* hi = WT + (size_t)mat*2*DM*DM;
  bf16* lo = hi + (size_t)DM*DM;
  int k0 = blockIdx.y*32, n0 = blockIdx.x*32;
  int tx = threadIdx.x & 31, ty = threadIdx.x >> 5;
  #pragma unroll
  for (int r = 0; r < 32; r += 8)
    t[ty + r][tx] = W[(size_t)(k0 + ty + r)*DM + n0 + tx];
  __syncthreads();
  #pragma unroll
  for (int r = 0; r < 32; r += 8){
    float w = t[tx][ty + r];
    bf16 h = __float2bfloat16(w);
    hi[(size_t)(n0 + ty + r)*DM + k0 + tx] = h;
    lo[(size_t)(n0 + ty + r)*DM + k0 + tx] = __float2bfloat16(w - __bfloat162float(h));
  }
}

__global__ void build_biasA(const float* __restrict__ bin, float* __restrict__ bias_pad){
  int i = blockIdx.x*256 + threadIdx.x;
  if (i >= 4*DM) return;
  int l = i/DM, n = i%DM;
  bias_pad[i] = (n < HID) ? bin[l*HID + n] : 0.f;
}

__global__ void build_c1aG(const float* __restrict__ W, bf16* __restrict__ WG){
  int i = blockIdx.x*256 + threadIdx.x;
  if (i >= 4*3*3*128*128) return;
  int k   = i & 127;
  int n   = (i >> 7) & 127;
  int tap = (i / 16384) % 3;
  int g   = (i / 49152) % 3;
  int l   = i / 147456;
  float v = 0.f;
  if (n < 114)
    v = W[(((size_t)l*HID + g*114 + n)*128 + k)*3 + tap];
  WG[i] = __float2bfloat16(v);
}

__global__ void build_c1bG(const float* __restrict__ W, bf16* __restrict__ WG){
  int i = blockIdx.x*256 + threadIdx.x;
  if (i >= 4*3*3*128*128) return;
  int k   = i & 127;
  int n   = (i >> 7) & 127;
  int tap = (i / 16384) % 3;
  int g   = (i / 49152) % 3;
  int l   = i / 147456;
  float v = 0.f;
  if (k < 114)
    v = W[(((size_t)l*DM + g*128 + n)*114 + k)*3 + tap];
  WG[i] = __float2bfloat16(v);
}

__global__ void build_c2T(const float* __restrict__ W, bf16* __restrict__ WT){
  int i = blockIdx.x*256 + threadIdx.x;
  if (i >= 4*2*3*128*128) return;
  int li = i & 127;
  int lo = (i >> 7) & 127;
  int t  = (i / 16384) % 3;
  int g  = (i / 49152) % 2;
  int l  = i / 98304;
  float v = 0.f;
  if (lo < 125 && li < 125)
    v = W[(((size_t)l*SEQ + g*125 + lo)*125 + li)*3 + t];
  WT[i] = __float2bfloat16(v);
}

// ---------------- fused probe + top-k + attention context per (b,h) ----------------
static constexpr int SSTR = 260;   // f32 stride
__global__ __launch_bounds__(256) void attn_fused(
    const bf16* __restrict__ Qhi, const bf16* __restrict__ Qlo,
    const bf16* __restrict__ Khi, const bf16* __restrict__ Klo,
    const bf16* __restrict__ V16, const int* __restrict__ idx,
    bf16* __restrict__ CTX, const bf16* __restrict__ zpage)
{
  __shared__ bf16  Qsh[32*64];
  __shared__ bf16  Qsl[32*64];
  __shared__ float Ssh[32*SSTR];
  __shared__ int   IDXsh[32*UU];
  __shared__ float Msh[256];
  __shared__ int   TOPsh[32];
  __shared__ float invsh[32];
  __shared__ float vpart[5][DHd];
  __shared__ float vmean[DHd];
  __shared__ int   mark[SEQ];
  const int bh = xcd_swz(blockIdx.x, Bb*NH);
  const int h = bh & 7; const int b = bh >> 3;
  const int tid = threadIdx.x;
  const int wid = tid >> 6, lane = tid & 63;
  const int scolz = swz_st(lane);
  const size_t base = (size_t)(b*SEQ)*DM + h*DHd;

  // K fragments into VGPRs (once)
  bf16x8 kfh[4][2] = {};
  bf16x8 kfl[4][2] = {};
  {
    const int colb = wid*64 + (lane & 15);
    const int kb   = (lane >> 4) * 8;
    #pragma unroll
    for (int n = 0; n < 4; n++){
      int col = colb + n*16;
      int cc  = (col < SEQ) ? col : (SEQ-1);
      const bf16* ph = Khi + base + (size_t)cc*DM;
      const bf16* pl = Klo + base + (size_t)cc*DM;
      kfh[n][0] = *(const bf16x8*)(ph + kb);
      kfl[n][0] = *(const bf16x8*)(pl + kb);
      if (kb + 32 < DHd){
        kfh[n][1] = *(const bf16x8*)(ph + kb + 32);
        kfl[n][1] = *(const bf16x8*)(pl + kb + 32);
      }
    }
  }
  for (int i = tid; i < SEQ; i += 256) mark[i] = -1;

  const int c_l = lane & 15, r4 = (lane >> 4) * 4;
  // ---- phase 1: probe over 8 Q-tiles ----
  for (int t = 0; t < 8; t++){
    const int r0 = t*32;
    {
      int row = r0 + wid*8 + (lane >> 3);
      bool v = (row < SEQ) && (scolz < DHd);
      const bf16* sh = v ? (Qhi + base + (size_t)row*DM + scolz) : zpage;
      const bf16* sl = v ? (Qlo + base + (size_t)row*DM + scolz) : zpage;
      gload16(sh, &Qsh[(wid*8)*64]);
      gload16(sl, &Qsl[(wid*8)*64]);
    }
    for (int i = tid; i < 32*UU; i += 256){
      int r = i / UU;
      int row = r0 + r;
      IDXsh[i] = (row < SEQ) ? idx[row*UU + (i - r*UU)] : 0;
    }
    __syncthreads();
    f32x4 acc[2][4] = {};
    __builtin_amdgcn_s_setprio(1);
    #pragma unroll
    for (int p = 0; p < 3; p++){
      const bf16* A = (p < 2) ? Qsh : Qsl;
      #pragma unroll
      for (int ks = 0; ks < 2; ks++){
        const int fo = swz_rd(ks, lane);
        bf16x8 af[2];
        #pragma unroll
        for (int m = 0; m < 2; m++)
          af[m] = *(const bf16x8*)&A[(m*16 + (lane & 15))*64 + fo];
        #pragma unroll
        for (int m = 0; m < 2; m++)
          #pragma unroll
          for (int n = 0; n < 4; n++){
            bf16x8 bg = (p == 1) ? kfl[n][ks] : kfh[n][ks];
            acc[m][n] = __builtin_amdgcn_mfma_f32_16x16x32_bf16(af[m], bg, acc[m][n], 0, 0, 0);
          }
      }
    }
    __builtin_amdgcn_s_setprio(0);
    #pragma unroll
    for (int m = 0; m < 2; m++)
      #pragma unroll
      for (int n = 0; n < 4; n++)
        #pragma unroll
        for (int r = 0; r < 4; r++)
          Ssh[(m*16 + r4 + r)*SSTR + wid*64 + n*16 + c_l] = acc[m][n][r];
    __syncthreads();
    {
      int rl = tid >> 3, s8 = tid & 7;
      int row = r0 + rl;
      float mx = -FLT_MAX, sm = 0.f;
      #pragma unroll
      for (int uu = 0; uu < 4; uu++){
        int u = s8 + uu*8;
        if (u < UU){
          int c = IDXsh[rl*UU + u];
          float v = Ssh[rl*SSTR + c];
          mx = fmaxf(mx, v); sm += v;
        }
      }
      #pragma unroll
      for (int off = 4; off; off >>= 1){
        mx = fmaxf(mx, __shfl_xor(mx, off));
        sm += __shfl_xor(sm, off);
      }
      if (s8 == 0 && row < SEQ) Msh[row] = mx - sm*(1.f/UU);
    }
    __syncthreads();
  }
  // ---- top-k (JAX tie-break) into TOPsh — single-wave, barrier-free ----
  if (wid == 0){
    float vals[4]; int ids[4];
    #pragma unroll
    for (int r = 0; r < 4; r++){
      int l = r*64 + lane;
      if (l < SEQ){ vals[r] = Msh[l]; ids[r] = l; }
      else        { vals[r] = -FLT_MAX; ids[r] = 1<<30; }
    }
    for (int sel = 0; sel < UU; sel++){
      float bv = -FLT_MAX; int bi = 1<<30;
      #pragma unroll
      for (int r = 0; r < 4; r++)
        if (vals[r] > bv || (vals[r] == bv && ids[r] < bi)){ bv = vals[r]; bi = ids[r]; }
      #pragma unroll
      for (int off = 32; off; off >>= 1){
        float ov = __shfl_xor(bv, off);
        int   oi = __shfl_xor(bi, off);
        if (ov > bv || (ov == bv && oi < bi)){ bv = ov; bi = oi; }
      }
      if (lane == 0) TOPsh[sel] = bi;
      #pragma unroll
      for (int r = 0; r < 4; r++) if (ids[r] == bi) vals[r] = -FLT_MAX;
    }
  }
  __syncthreads();
  if (tid < UU) mark[TOPsh[tid]] = tid;

  // ---- phase 2: ctx for top-30 rows ----
  {
    int row = wid*8 + (lane >> 3);
    bool v = (row < UU) && (scolz < DHd);
    int tr = v ? TOPsh[row] : 0;
    const bf16* sh = v ? (Qhi + base + (size_t)tr*DM + scolz) : zpage;
    const bf16* sl = v ? (Qlo + base + (size_t)tr*DM + scolz) : zpage;
    gload16(sh, &Qsh[(wid*8)*64]);
    gload16(sl, &Qsl[(wid*8)*64]);
  }
  __syncthreads();
  {
    f32x4 acc[2][4] = {};
    __builtin_amdgcn_s_setprio(1);
    #pragma unroll
    for (int p = 0; p < 3; p++){
      const bf16* A = (p < 2) ? Qsh : Qsl;
      #pragma unroll
      for (int ks = 0; ks < 2; ks++){
        const int fo = swz_rd(ks, lane);
        bf16x8 af[2];
        #pragma unroll
        for (int m = 0; m < 2; m++)
          af[m] = *(const bf16x8*)&A[(m*16 + (lane & 15))*64 + fo];
        #pragma unroll
        for (int m = 0; m < 2; m++)
          #pragma unroll
          for (int n = 0; n < 4; n++){
            bf16x8 bg = (p == 1) ? kfl[n][ks] : kfh[n][ks];
            acc[m][n] = __builtin_amdgcn_mfma_f32_16x16x32_bf16(af[m], bg, acc[m][n], 0, 0, 0);
          }
      }
    }
    __builtin_amdgcn_s_setprio(0);
    #pragma unroll
    for (int m = 0; m < 2; m++)
      #pragma unroll
      for (int n = 0; n < 4; n++)
        #pragma unroll
        for (int r = 0; r < 4; r++)
          Ssh[(m*16 + r4 + r)*SSTR + wid*64 + n*16 + c_l] = acc[m][n][r];
  }
  __syncthreads();
  {
    const float scale = 0.14433756729740643f;
    for (int rr = 0; rr < 8; rr++){
      int row = wid*8 + rr;
      float* Sr = &Ssh[row*SSTR];
      if (row < UU){
        float xs[4];
        #pragma unroll
        for (int j = 0; j < 4; j++){
          int c = lane + 64*j;
          xs[j] = (c < SEQ) ? Sr[c]*scale : -FLT_MAX;
        }
        float mx = fmaxf(fmaxf(xs[0],xs[1]), fmaxf(xs[2],xs[3]));
        #pragma unroll
        for (int off = 32; off; off >>= 1) mx = fmaxf(mx, __shfl_xor(mx, off));
        float sm = 0.f;
        #pragma unroll
        for (int j = 0; j < 4; j++){
          int c = lane + 64*j;
          float e = (c < SEQ) ? __expf(xs[j]-mx) : 0.f;
          Sr[c] = e;
          sm += e;
        }
        #pragma unroll
        for (int off = 32; off; off >>= 1) sm += __shfl_xor(sm, off);
        if (lane == 0) invsh[row] = 1.f/sm;
      } else {
        #pragma unroll
        for (int j = 0; j < 4; j++) Sr[lane + 64*j] = 0.f;
      }
    }
    // vmean partials streamed from global V (same 50-token ascending order -> bit-identical)
    if (tid < 240){
      int dh = tid % DHd, pr = tid / DHd;
      const bf16* vp = V16 + base + dh;
      float s = 0.f;
      #pragma unroll 10
      for (int z = 0; z < 50; z++){
        int j = pr*50 + z;
        s += __bfloat162float(vp[(size_t)j*DM]);
      }
      vpart[pr][dh] = s;
    }
  }
  __syncthreads();
  if (tid < DHd)
    vmean[tid] = (vpart[0][tid]+vpart[1][tid]+vpart[2][tid]+vpart[3][tid]+vpart[4][tid]) * (1.f/SEQ);

  if (wid < 3){
    const int dh0 = wid*16;
    const int dh  = dh0 + c_l;
    // hoist all PV B-fragments from global (L1/L2-resident V slice)
    bf16x8 bvv[8];
    #pragma unroll
    for (int kc = 0; kc < 8; kc++){
      int j0 = kc*32 + (lane >> 4)*8;
      #pragma unroll
      for (int i = 0; i < 8; i++){
        int j = j0 + i;
        bf16 vv = (j < SEQ) ? V16[base + (size_t)j*DM + dh] : __float2bfloat16(0.f);
        bvv[kc][i] = *reinterpret_cast<short*>(&vv);
      }
    }
    f32x4 acc2[2] = {};
    __builtin_amdgcn_s_setprio(1);
    for (int kc = 0; kc < 8; kc++){
      #pragma unroll
      for (int m = 0; m < 2; m++){
        const float* pr = &Ssh[(m*16 + (lane & 15))*SSTR + kc*32 + (lane >> 4)*8];
        bf16x8 pa;
        #pragma unroll
        for (int i = 0; i < 8; i++){
          bf16 hh = __float2bfloat16(pr[i]);
          pa[i] = *reinterpret_cast<short*>(&hh);
        }
        acc2[m] = __builtin_amdgcn_mfma_f32_16x16x32_bf16(pa, bvv[kc], acc2[m], 0, 0, 0);
      }
    }
    __builtin_amdgcn_s_setprio(0);
    #pragma unroll
    for (int m = 0; m < 2; m++)
      #pragma unroll
      for (int r = 0; r < 4; r++){
        int u = m*16 + r4 + r;
        if (u < UU){
          float val = acc2[m][r] * invsh[u];
          CTX[(size_t)(b*SEQ + TOPsh[u])*DM + h*DHd + dh0 + c_l] = __float2bfloat16(val);
        }
      }
  }
  __syncthreads();
  {
    // incremental (l,dh) indexing: i = tid + k*256 ; 256 = 5*48 + 16
    int l = tid / DHd, dh = tid - l*DHd;
    for (int i = tid; i < SEQ*DHd; i += 256){
      if (mark[l] < 0)
        CTX[(size_t)(b*SEQ + l)*DM + h*DHd + dh] = __float2bfloat16(vmean[dh]);
      dh += 16; l += 5;
      if (dh >= DHd){ dh -= DHd; l += 1; }
    }
  }
}

// ---------------- final: max over L -> LN(ln2) -> FC ----------------
__global__ __launch_bounds__(384) void final_kernel(const float* __restrict__ Hin,
    const float* __restrict__ w, const float* __restrict__ bparm,
    const float* __restrict__ fcw, const float* __restrict__ fcb, float* __restrict__ out){
  __shared__ float red[8];
  __shared__ float ybuf[DM];
  int b = blockIdx.x; int d = threadIdx.x;
  const float* hp = Hin + (size_t)b*SEQ*DM + d;
  float mx = -FLT_MAX;
  for (int l=0;l<SEQ;l++) mx = fmaxf(mx, hp[(size_t)l*DM]);
  float mu = block_sum(mx, red) * (1.f/DM);
  float diff = mx - mu;
  float var = block_sum(diff*diff, red) * (1.f/DM);
  float y = diff * rsqrtf(var + 1e-5f) * w[d] + bparm[d];
  ybuf[d] = y;
  __syncthreads();
  if (d < 10){
    float acc = fcb[d];
    for (int k=0;k<DM;k++) acc += ybuf[k] * fcw[k*10 + d];
    out[b*10 + d] = acc;
  }
}

// ---------------- host orchestration ----------------
extern "C" void kernel_launch(void* const* d_in, const int* in_sizes, int n_in,
                              void* d_out, int out_size, void* d_ws, size_t ws_size,
                              hipStream_t stream) {
  const float* x     = (const float*)d_in[0];
  const float* pos   = (const float*)d_in[1];
  const float* lniw  = (const float*)d_in[2];
  const float* lnib  = (const float*)d_in[3];
  const float* lnAw  = (const float*)d_in[4];
  const float* lnAb  = (const float*)d_in[5];
  const float* Wq    = (const float*)d_in[6];
  const float* bq    = (const float*)d_in[7];
  const float* Wk    = (const float*)d_in[8];
  const float* bk    = (const float*)d_in[9];
  const float* Wv    = (const float*)d_in[10];
  const float* bv    = (const float*)d_in[11];
  const float* Wo    = (const float*)d_in[12];
  const float* bo    = (const float*)d_in[13];
  const float* lnBw  = (const float*)d_in[14];
  const float* lnBb  = (const float*)d_in[15];
  const float* c1aw  = (const float*)d_in[16];
  const float* c1ab  = (const float*)d_in[17];
  const float* c1bw  = (const float*)d_in[18];
  const float* c1bb  = (const float*)d_in[19];
  const float* lnCw  = (const float*)d_in[20];
  const float* lnCb  = (const float*)d_in[21];
  const float* c2w   = (const float*)d_in[22];
  const float* c2b   = (const float*)d_in[23];
  const float* ln2w  = (const float*)d_in[24];
  const float* ln2b  = (const float*)d_in[25];
  const float* fcw   = (const float*)d_in[26];
  const float* fcb   = (const float*)d_in[27];
  float* out = (float*)d_out;

  const size_t ACT  = (size_t)Bb*SEQ*DM;        // 12,288,000
  float* Xb  = (float*)d_ws;
  float* Hb  = Xb  + ACT;
  float* Qb  = Hb  + ACT;
  float* Kb  = Qb  + ACT;
  float* Vb  = Kb  + ACT;
  float* biasA = Vb + ACT;
  int*   TOP = (int*)(biasA + 4*DM);            // unused (layout stability)
  int*   IDX = TOP + (size_t)Bb*NH*UU;
  bf16*  Hb16 = (bf16*)(IDX + 4*7500);
  bf16*  G1   = Hb16 + ACT;
  bf16*  WvT  = G1   + ACT;
  bf16*  WoT  = WvT  + (size_t)4*DM*DM;
  bf16*  WaG  = WoT  + (size_t)4*DM*DM;
  bf16*  WbG  = WaG  + (size_t)12*DM*DM;
  bf16*  WqkT = WbG  + (size_t)12*DM*DM;
  bf16*  W2T  = WqkT + (size_t)16*DM*DM;
  bf16*  zp   = W2T  + (size_t)4*2*3*128*128;

  bf16* Qhi = (bf16*)Qb; bf16* Qlo = Qhi + ACT;
  bf16* Khi = (bf16*)Kb; bf16* Klo = Khi + ACT;
  bf16* V16 = (bf16*)Vb;

  zfill<<<dim3(1), dim3(256), 0, stream>>>(zp);
  hipMemsetAsync(G1, 0, ACT*sizeof(bf16), stream);
  idx_kernel<<<dim3(118), dim3(256), 0, stream>>>(IDX);
  build_projT<<<dim3(12,12,8), dim3(256), 0, stream>>>(Wv, Wo, WvT, WoT);
  build_qkhl<<<dim3(12,12,8), dim3(256), 0, stream>>>(Wq, Wk, WqkT);
  build_biasA<<<dim3(6), dim3(256), 0, stream>>>(c1ab, biasA);
  build_c1aG<<<dim3(2304), dim3(256), 0, stream>>>(c1aw, WaG);
  build_c1bG<<<dim3(2304), dim3(256), 0, stream>>>(c1bw, WbG);
  build_c2T<<<dim3(1536), dim3(256), 0, stream>>>(c2w, W2T);
  pool_ln_pos<<<dim3(32000), dim3(384), 0, stream>>>(x, pos, lniw, lnib, Xb);

  for (int l = 0; l < 4; l++){
    const size_t wofs = (size_t)l*DM*DM;
    bf16* Alo16 = (bf16*)Hb;
    bf16* CTX16 = Hb16;
    bf16* HTb   = (bf16*)Qb;
    ln_wave<2><<<dim3(8000), dim3(256), 0, stream>>>(Xb, (float*)nullptr, Hb16, Alo16, lnAw + l*DM, lnAb + l*DM);
    mfma_qk2<<<dim3(1500), dim3(256), 0, stream>>>(Hb16, Alo16,
        WqkT + (size_t)l*2*DM*DM, WqkT + (size_t)(4+l)*2*DM*DM,
        bq + l*DM, bk + l*DM, Qhi, Qlo, Khi, Klo);
    mfma_gemm<3><<<dim3(750), dim3(256), 0, stream>>>(Hb16, WvT + wofs, bv + l*DM, (float*)nullptr, V16, zp);
    attn_fused<<<dim3(Bb*NH), dim3(256), 0, stream>>>(Qhi, Qlo, Khi, Klo, V16, IDX + l*7500, CTX16, zp);
    mfma_gemm<1><<<dim3(750), dim3(256), 0, stream>>>(CTX16, WoT + wofs, bo + l*DM, Xb, (bf16*)nullptr, zp);

    ln_wave<1><<<dim3(8000), dim3(256), 0, stream>>>(Xb, (float*)nullptr, Hb16, (bf16*)nullptr, lnBw + l*DM, lnBb + l*DM);
    mfma_c1g<2,128><<<dim3(750), dim3(256), 0, stream>>>(Hb16, WaG + (size_t)l*3*3*128*128, biasA + l*DM, (float*)nullptr, G1, zp);
    mfma_c1g<1,114><<<dim3(750), dim3(256), 0, stream>>>(G1, WbG + (size_t)l*3*3*128*128, c1bb + l*DM, Xb, (bf16*)nullptr, zp);

    ln_wave<1><<<dim3(8000), dim3(256), 0, stream>>>(Xb, (float*)nullptr, Hb16, (bf16*)nullptr, lnCw + l*DM, lnCb + l*DM);
    transpose_ht<<<dim3(6,4,Bb), dim3(256), 0, stream>>>(Hb16, HTb);
    conv2_mfma<<<dim3(768), dim3(256), 0, stream>>>(HTb, W2T + (size_t)l*2*3*128*128, c2b + l*SEQ, Xb, zp);
  }

  ln_wave<0><<<dim3(8000), dim3(256), 0, stream>>>(Xb, Hb, (bf16*)nullptr, (bf16*)nullptr, ln2w, ln2b);
  final_kernel<<<dim3(Bb), dim3(384), 0, stream>>>(Hb, ln2w, ln2b, fcw, fcb, out);
}